// Round 6
// baseline (231.723 us; speedup 1.0000x reference)
//
#include <hip/hip_runtime.h>

#define BB 8
#define ENC_C 64
#define DEC_C 128
#define HH 128
#define WW 128

typedef unsigned short ushort_t;
typedef __attribute__((ext_vector_type(8))) short short8;
typedef __attribute__((ext_vector_type(4))) float f32x4;

static __device__ __forceinline__ ushort_t f2bf(float x) {
  unsigned int u = __builtin_bit_cast(unsigned int, x);
  u += 0x7fff + ((u >> 16) & 1);   // round-to-nearest-even
  return (ushort_t)(u >> 16);
}
static __device__ __forceinline__ float bf2f(ushort_t v) {
  unsigned int u = ((unsigned int)v) << 16;
  return __builtin_bit_cast(float, u);
}

// ---------------------------------------------------------------------------
// Kernel 0: pack weight fragments (bf16).
//   blk 0..143   : conv_w (K=1152)  -> packedC
//   blk 144..159 : W_attn (K=128)   -> packedA
//   blk 160..175 : W_dec  (K=128)   -> packedQ
//   blk 176..183 : W_enc  (K=64)    -> packedK
// Frag: lane l, elem j holds W[k = ks*32 + (l>>4)*8 + j][n = nf*16 + (l&15)].
// ---------------------------------------------------------------------------
__global__ __launch_bounds__(64) void pack_w_kernel(
    const float* __restrict__ conv_w, const float* __restrict__ W_attn,
    const float* __restrict__ W_dec, const float* __restrict__ W_enc,
    ushort_t* __restrict__ packedC, ushort_t* __restrict__ packedA,
    ushort_t* __restrict__ packedQ, ushort_t* __restrict__ packedK)
{
  const int blk = blockIdx.x;
  const int l = threadIdx.x;
  const float* W;
  ushort_t* dst;
  int bb;
  if (blk < 144) {
    const int kstep = blk >> 2, nf = blk & 3;
    const int tap = kstep >> 2, dstep = kstep & 3;
    const int n = nf * 16 + (l & 15);
    const int dbase = dstep * 32 + (l >> 4) * 8;
    ushort_t v[8];
    #pragma unroll
    for (int j = 0; j < 8; ++j)
      v[j] = f2bf(conv_w[(tap * DEC_C + dbase + j) * 64 + n]);
    ushort_t* d = packedC + ((long)blk * 64 + l) * 8;
    #pragma unroll
    for (int j = 0; j < 8; ++j) d[j] = v[j];
    return;
  } else if (blk < 160) {
    W = W_attn; dst = packedA; bb = blk - 144;
  } else if (blk < 176) {
    W = W_dec;  dst = packedQ; bb = blk - 160;
  } else {
    W = W_enc;  dst = packedK; bb = blk - 176;
  }
  const int ks = bb >> 2, nf = bb & 3;
  const int n = nf * 16 + (l & 15);
  const int kbase = ks * 32 + (l >> 4) * 8;
  ushort_t v[8];
  #pragma unroll
  for (int j = 0; j < 8; ++j)
    v[j] = f2bf(W[(kbase + j) * 64 + n]);
  ushort_t* d = dst + ((long)bb * 64 + l) * 8;
  #pragma unroll
  for (int j = 0; j < 8; ++j) d[j] = v[j];
}

// ---------------------------------------------------------------------------
// Kernel 1: per (b,h) row. MFMA (A = pixel frags from LDS, B = packed W).
// Outputs q/k NHWC bf16 (+bias), enc_t NHWC bf16, dec_t NHWC bf16.
// ---------------------------------------------------------------------------
__global__ __launch_bounds__(256, 4) void prep_kernel(
    const float* __restrict__ enc, const float* __restrict__ dec,
    const ushort_t* __restrict__ packedQ, const ushort_t* __restrict__ packedK,
    const float* __restrict__ b_enc, const float* __restrict__ b_dec,
    ushort_t* __restrict__ q_nhwc, ushort_t* __restrict__ k_nhwc,
    ushort_t* __restrict__ enc_t, ushort_t* __restrict__ dec_t)
{
  __shared__ float smem[WW * 68];
  const int bh = blockIdx.x;
  const int b = bh >> 7, h = bh & 127;
  const int tid = threadIdx.x;
  const int l = tid & 63;
  const int wv = tid >> 6;
  const int pix0 = wv * 32;
  const int col = l & 15, kg = l >> 4;

  // ---- encoder tile [w][c] f32 ----
  #pragma unroll
  for (int i = 0; i < 32; ++i) {
    int idx = tid + i * 256;
    int cc = idx >> 7, wl = idx & 127;
    smem[wl * 68 + cc] = enc[((b * ENC_C + cc) * HH + h) * WW + wl];
  }
  __syncthreads();

  // enc_t NHWC bf16
  #pragma unroll
  for (int i = 0; i < 32; ++i) {
    int idx = tid + i * 256;
    int wl = idx >> 6, cc = idx & 63;
    enc_t[((long)bh * WW + wl) * 64 + cc] = f2bf(smem[wl * 68 + cc]);
  }

  // k = enc @ W_enc  (A = pixels, D row = pixel -> NHWC)
  f32x4 acck[2][4];
  #pragma unroll
  for (int mf = 0; mf < 2; ++mf)
    #pragma unroll
    for (int nf = 0; nf < 4; ++nf)
      acck[mf][nf] = (f32x4){0.f, 0.f, 0.f, 0.f};

  #pragma unroll
  for (int ks = 0; ks < 2; ++ks) {
    short8 afr[2];
    #pragma unroll
    for (int mf = 0; mf < 2; ++mf) {
      const int pix = pix0 + mf * 16 + col;
      const float4* p = (const float4*)&smem[pix * 68 + ks * 32 + kg * 8];
      float4 x0 = p[0], x1 = p[1];
      short8 v;
      v[0] = (short)f2bf(x0.x); v[1] = (short)f2bf(x0.y);
      v[2] = (short)f2bf(x0.z); v[3] = (short)f2bf(x0.w);
      v[4] = (short)f2bf(x1.x); v[5] = (short)f2bf(x1.y);
      v[6] = (short)f2bf(x1.z); v[7] = (short)f2bf(x1.w);
      afr[mf] = v;
    }
    #pragma unroll
    for (int nf = 0; nf < 4; ++nf) {
      const short8 bfr =
          *(const short8*)(packedK + ((long)(ks * 4 + nf) * 64 + l) * 8);
      acck[0][nf] = __builtin_amdgcn_mfma_f32_16x16x32_bf16(
          afr[0], bfr, acck[0][nf], 0, 0, 0);
      acck[1][nf] = __builtin_amdgcn_mfma_f32_16x16x32_bf16(
          afr[1], bfr, acck[1][nf], 0, 0, 0);
    }
  }
  // store k NHWC bf16
  #pragma unroll
  for (int mf = 0; mf < 2; ++mf)
    #pragma unroll
    for (int nf = 0; nf < 4; ++nf)
      #pragma unroll
      for (int r = 0; r < 4; ++r) {
        const int pix = pix0 + mf * 16 + kg * 4 + r;
        const int c = nf * 16 + col;
        k_nhwc[((long)bh * WW + pix) * 64 + c] = f2bf(acck[mf][nf][r] + b_enc[c]);
      }
  __syncthreads();

  // ---- decoder tile, two 64-channel halves ----
  f32x4 accq[2][4];
  #pragma unroll
  for (int mf = 0; mf < 2; ++mf)
    #pragma unroll
    for (int nf = 0; nf < 4; ++nf)
      accq[mf][nf] = (f32x4){0.f, 0.f, 0.f, 0.f};

  #pragma unroll
  for (int hf = 0; hf < 2; ++hf) {
    #pragma unroll
    for (int i = 0; i < 32; ++i) {
      int idx = tid + i * 256;
      int cc = idx >> 7, wl = idx & 127;
      smem[wl * 68 + cc] = dec[((b * DEC_C + hf * 64 + cc) * HH + h) * WW + wl];
    }
    __syncthreads();

    // dec_t NHWC bf16
    #pragma unroll
    for (int i = 0; i < 32; ++i) {
      int idx = tid + i * 256;
      int wl = idx >> 6, cc = idx & 63;
      dec_t[((long)bh * WW + wl) * DEC_C + hf * 64 + cc] =
          f2bf(smem[wl * 68 + cc]);
    }

    #pragma unroll
    for (int ks2 = 0; ks2 < 2; ++ks2) {
      const int ks = hf * 2 + ks2;
      short8 afr[2];
      #pragma unroll
      for (int mf = 0; mf < 2; ++mf) {
        const int pix = pix0 + mf * 16 + col;
        const float4* p = (const float4*)&smem[pix * 68 + ks2 * 32 + kg * 8];
        float4 x0 = p[0], x1 = p[1];
        short8 v;
        v[0] = (short)f2bf(x0.x); v[1] = (short)f2bf(x0.y);
        v[2] = (short)f2bf(x0.z); v[3] = (short)f2bf(x0.w);
        v[4] = (short)f2bf(x1.x); v[5] = (short)f2bf(x1.y);
        v[6] = (short)f2bf(x1.z); v[7] = (short)f2bf(x1.w);
        afr[mf] = v;
      }
      #pragma unroll
      for (int nf = 0; nf < 4; ++nf) {
        const short8 bfr =
            *(const short8*)(packedQ + ((long)(ks * 4 + nf) * 64 + l) * 8);
        accq[0][nf] = __builtin_amdgcn_mfma_f32_16x16x32_bf16(
            afr[0], bfr, accq[0][nf], 0, 0, 0);
        accq[1][nf] = __builtin_amdgcn_mfma_f32_16x16x32_bf16(
            afr[1], bfr, accq[1][nf], 0, 0, 0);
      }
    }
    __syncthreads();
  }

  // store q NHWC bf16
  #pragma unroll
  for (int mf = 0; mf < 2; ++mf)
    #pragma unroll
    for (int nf = 0; nf < 4; ++nf)
      #pragma unroll
      for (int r = 0; r < 4; ++r) {
        const int pix = pix0 + mf * 16 + kg * 4 + r;
        const int c = nf * 16 + col;
        q_nhwc[((long)bh * WW + pix) * 64 + c] = f2bf(accq[mf][nf][r] + b_dec[c]);
      }
}

// ---------------------------------------------------------------------------
// Kernel 2: attention, thread = pixel, all-NHWC bf16 vector loads.
// Channel-chunked (4 x 16) to bound code size and registers; all array
// indexing compile-time static.
// ---------------------------------------------------------------------------
__global__ __launch_bounds__(256, 2) void attn_kernel(
    const ushort_t* __restrict__ q_nhwc, const ushort_t* __restrict__ k_nhwc,
    const ushort_t* __restrict__ enc_t, const float* __restrict__ W_agg,
    const float* __restrict__ b_agg, ushort_t* __restrict__ att)
{
  const int nwg = gridDim.x;                 // 512, divisible by 8
  const int cpx = nwg >> 3;
  const int bid = blockIdx.x;
  const int swz = (bid & 7) * cpx + (bid >> 3);   // XCD-contiguous pixels
  const int t = swz * 256 + threadIdx.x;
  const int h = (t >> 7) & 127;
  const int w = t & 127;

  int off[9]; bool valid[9];
  #pragma unroll
  for (int n = 0; n < 9; ++n) {
    const int dh = n / 3 - 1, dw = n % 3 - 1;
    const int nh = h + dh, nw = w + dw;
    valid[n] = (nh >= 0 && nh < HH && nw >= 0 && nw < WW);
    const int nhc = min(max(nh, 0), HH - 1);
    const int nwc = min(max(nw, 0), WW - 1);
    off[n] = (t & ~16383) + nhc * WW + nwc;  // same batch, clamped pixel
  }

  const short8* qp = (const short8*)(q_nhwc + ((long)t << 6));
  const short8* kp[9];
  const short8* ep[9];
  #pragma unroll
  for (int n = 0; n < 9; ++n) {
    kp[n] = (const short8*)(k_nhwc + ((long)off[n] << 6));
    ep[n] = (const short8*)(enc_t + ((long)off[n] << 6));
  }

  // ---- scores: 4 channel-chunks of 16 ----
  float s[9];
  #pragma unroll
  for (int n = 0; n < 9; ++n) s[n] = 0.f;

  for (int ci = 0; ci < 4; ++ci) {        // dynamic: bounds code size
    const short8 qa = qp[2 * ci], qb = qp[2 * ci + 1];
    float wa[16];
    #pragma unroll
    for (int e = 0; e < 16; ++e) wa[e] = W_agg[ci * 16 + e];  // s_load
    #pragma unroll
    for (int n = 0; n < 9; ++n) {
      const short8 ka = kp[n][2 * ci], kb = kp[n][2 * ci + 1];
      float sc = 0.f;
      #pragma unroll
      for (int e = 0; e < 8; ++e) {
        float x = bf2f((ushort_t)qa[e]) + bf2f((ushort_t)ka[e]);
        x = fminf(fmaxf(x, -15.f), 15.f);
        float z = __builtin_amdgcn_exp2f(x * 2.88539008f);
        float tt = __builtin_fmaf(-2.f, __builtin_amdgcn_rcpf(z + 1.f), 1.f);
        sc = __builtin_fmaf(tt, wa[e], sc);
      }
      #pragma unroll
      for (int e = 0; e < 8; ++e) {
        float x = bf2f((ushort_t)qb[e]) + bf2f((ushort_t)kb[e]);
        x = fminf(fmaxf(x, -15.f), 15.f);
        float z = __builtin_amdgcn_exp2f(x * 2.88539008f);
        float tt = __builtin_fmaf(-2.f, __builtin_amdgcn_rcpf(z + 1.f), 1.f);
        sc = __builtin_fmaf(tt, wa[8 + e], sc);
      }
      s[n] += sc;
    }
  }

  // ---- masked softmax ----
  const float bagg = b_agg[0];
  float m = -1e30f;
  #pragma unroll
  for (int n = 0; n < 9; ++n) {
    s[n] = valid[n] ? (s[n] + bagg) : -1e30f;
    m = fmaxf(m, s[n]);
  }
  float attw[9]; float denom = 0.f;
  #pragma unroll
  for (int n = 0; n < 9; ++n) {
    attw[n] = __builtin_amdgcn_exp2f((s[n] - m) * 1.44269504f);
    denom += attw[n];
  }
  const float inv = __builtin_amdgcn_rcpf(denom);
  #pragma unroll
  for (int n = 0; n < 9; ++n) attw[n] *= inv;   // invalid -> exactly 0

  // ---- weighted encoder sum, chunked; contiguous 128B/lane store ----
  short8* op = (short8*)(att + ((long)t << 6));
  for (int ci = 0; ci < 4; ++ci) {
    float a16[16];
    #pragma unroll
    for (int e = 0; e < 16; ++e) a16[e] = 0.f;
    #pragma unroll
    for (int n = 0; n < 9; ++n) {
      const short8 ea = ep[n][2 * ci], eb = ep[n][2 * ci + 1];
      #pragma unroll
      for (int e = 0; e < 8; ++e)
        a16[e] = __builtin_fmaf(attw[n], bf2f((ushort_t)ea[e]), a16[e]);
      #pragma unroll
      for (int e = 0; e < 8; ++e)
        a16[8 + e] = __builtin_fmaf(attw[n], bf2f((ushort_t)eb[e]), a16[8 + e]);
    }
    short8 o0, o1;
    #pragma unroll
    for (int e = 0; e < 8; ++e) {
      o0[e] = (short)f2bf(a16[e]);
      o1[e] = (short)f2bf(a16[8 + e]);
    }
    op[2 * ci] = o0;
    op[2 * ci + 1] = o1;
  }
}

// ---------------------------------------------------------------------------
// Kernel 3: fused conv(3x3 MFMA) + out = LeakyReLU([vals;attn]@W_attn + b).
// (256,4): VGPR cap 128 == full residency; deeper load pipelining.
// XCD swizzle: h-adjacent blocks share dec_t rows in one XCD's L2.
// ---------------------------------------------------------------------------
__global__ __launch_bounds__(256, 4) void conv_out_kernel(
    const ushort_t* __restrict__ dec_t, const ushort_t* __restrict__ packedC,
    const float* __restrict__ conv_b, const ushort_t* __restrict__ attn_nhwc,
    const ushort_t* __restrict__ packedA, const float* __restrict__ b_attn,
    float* __restrict__ out)
{
  __shared__ ushort_t vlds[WW * 68];
  const int nwg = gridDim.x;                 // 1024, divisible by 8
  const int cpx = nwg >> 3;
  const int bid = blockIdx.x;
  const int bh = (bid & 7) * cpx + (bid >> 3);
  const int b = bh >> 7, h = bh & 127;
  const int tid = threadIdx.x;
  const int l = tid & 63;
  const int wv = tid >> 6;
  const int pix0 = wv * 32;
  const int col = l & 15, kg = l >> 4;

  // ---- conv phase ----
  f32x4 acc[2][4];
  #pragma unroll
  for (int mf = 0; mf < 2; ++mf)
    #pragma unroll
    for (int nf = 0; nf < 4; ++nf)
      acc[mf][nf] = (f32x4){0.f, 0.f, 0.f, 0.f};

  #pragma unroll
  for (int kh = 0; kh < 3; ++kh) {
    const int hh = h + kh - 1;
    if (hh < 0 || hh >= HH) continue;   // block-uniform skip
    const ushort_t* arow = dec_t + ((long)(b * HH + hh) * WW) * DEC_C;
    #pragma unroll
    for (int ds = 0; ds < 4; ++ds) {
      const int d0 = ds * 32;
      // hoist all 6 A-frags (3 kw x 2 mf) for this (kh, ds)
      short8 afr[3][2];
      #pragma unroll
      for (int kw = 0; kw < 3; ++kw)
        #pragma unroll
        for (int mf = 0; mf < 2; ++mf) {
          const int wp = pix0 + mf * 16 + col + kw - 1;
          short8 v = {0, 0, 0, 0, 0, 0, 0, 0};
          if (wp >= 0 && wp < WW)
            v = *(const short8*)(arow + (long)wp * DEC_C + d0 + kg * 8);
          afr[kw][mf] = v;
        }
      #pragma unroll
      for (int kw = 0; kw < 3; ++kw) {
        const int kstep = (kh * 3 + kw) * 4 + ds;
        #pragma unroll
        for (int nf = 0; nf < 4; ++nf) {
          const short8 bfr =
              *(const short8*)(packedC + ((long)(kstep * 4 + nf) * 64 + l) * 8);
          acc[0][nf] = __builtin_amdgcn_mfma_f32_16x16x32_bf16(
              afr[kw][0], bfr, acc[0][nf], 0, 0, 0);
          acc[1][nf] = __builtin_amdgcn_mfma_f32_16x16x32_bf16(
              afr[kw][1], bfr, acc[1][nf], 0, 0, 0);
        }
      }
    }
  }

  // vals -> LDS bf16 [pix][c] stride 68
  #pragma unroll
  for (int mf = 0; mf < 2; ++mf)
    #pragma unroll
    for (int nf = 0; nf < 4; ++nf)
      #pragma unroll
      for (int r = 0; r < 4; ++r) {
        const int pix = pix0 + mf * 16 + kg * 4 + r;
        const int c = nf * 16 + col;
        vlds[pix * 68 + c] = f2bf(acc[mf][nf][r] + conv_b[c]);
      }
  __syncthreads();

  // ---- out phase (swapped: A = W_attn frags, B = cat^T; D = (ch, pix)) ----
  f32x4 ao[4][2];
  #pragma unroll
  for (int mf = 0; mf < 4; ++mf)
    #pragma unroll
    for (int pf = 0; pf < 2; ++pf)
      ao[mf][pf] = (f32x4){0.f, 0.f, 0.f, 0.f};

  #pragma unroll
  for (int ks = 0; ks < 4; ++ks) {
    short8 bfr[2];
    #pragma unroll
    for (int pf = 0; pf < 2; ++pf) {
      const int pix = pix0 + pf * 16 + col;
      short8 v;
      if (ks < 2) {
        const int k0 = ks * 32 + kg * 8;
        #pragma unroll
        for (int e = 0; e < 8; ++e) v[e] = (short)vlds[pix * 68 + k0 + e];
      } else {
        v = *(const short8*)(attn_nhwc + ((long)bh * WW + pix) * 64 +
                             (ks - 2) * 32 + kg * 8);
      }
      bfr[pf] = v;
    }
    #pragma unroll
    for (int mf = 0; mf < 4; ++mf) {
      const short8 afr =
          *(const short8*)(packedA + ((long)(ks * 4 + mf) * 64 + l) * 8);
      #pragma unroll
      for (int pf = 0; pf < 2; ++pf)
        ao[mf][pf] = __builtin_amdgcn_mfma_f32_16x16x32_bf16(
            afr, bfr[pf], ao[mf][pf], 0, 0, 0);
    }
  }

  // direct NCHW f32 stores
  #pragma unroll
  for (int mf = 0; mf < 4; ++mf)
    #pragma unroll
    for (int pf = 0; pf < 2; ++pf)
      #pragma unroll
      for (int r = 0; r < 4; ++r) {
        const int n = mf * 16 + kg * 4 + r;
        const int pix = pix0 + pf * 16 + col;
        float o = ao[mf][pf][r] + b_attn[n];
        o = (o >= 0.f) ? o : 0.2f * o;
        out[((long)(b * ENC_C + n) * HH + h) * WW + pix] = o;
      }
}

// ---------------------------------------------------------------------------
extern "C" void kernel_launch(void* const* d_in, const int* in_sizes, int n_in,
                              void* d_out, int out_size, void* d_ws, size_t ws_size,
                              hipStream_t stream) {
  const float* enc    = (const float*)d_in[0];
  const float* dec    = (const float*)d_in[1];
  const float* W_enc  = (const float*)d_in[2];
  const float* b_enc  = (const float*)d_in[3];
  const float* W_dec  = (const float*)d_in[4];
  const float* b_dec  = (const float*)d_in[5];
  const float* W_agg  = (const float*)d_in[6];
  const float* b_agg  = (const float*)d_in[7];
  const float* W_attn = (const float*)d_in[8];
  const float* b_attn = (const float*)d_in[9];
  const float* conv_w = (const float*)d_in[10];
  const float* conv_b = (const float*)d_in[11];
  float* out = (float*)d_out;

  const long npix = (long)BB * HH * WW;               // 131072
  ushort_t* q_bf    = (ushort_t*)d_ws;                // [npix][64] bf16 NHWC
  ushort_t* k_bf    = q_bf + npix * 64;               // [npix][64]
  ushort_t* enc_t   = k_bf + npix * 64;               // [npix][64]
  ushort_t* dec_t   = enc_t + npix * 64;              // [npix][128]
  ushort_t* att     = dec_t + npix * 128;             // [npix][64]
  ushort_t* packedC = att + npix * 64;                // conv W frags
  ushort_t* packedA = packedC + 144 * 64 * 8;
  ushort_t* packedQ = packedA + 16 * 64 * 8;
  ushort_t* packedK = packedQ + 16 * 64 * 8;

  hipLaunchKernelGGL(pack_w_kernel, dim3(184), dim3(64), 0, stream,
                     conv_w, W_attn, W_dec, W_enc, packedC, packedA, packedQ, packedK);
  hipLaunchKernelGGL(prep_kernel, dim3(BB * HH), dim3(256), 0, stream,
                     enc, dec, packedQ, packedK, b_enc, b_dec, q_bf, k_bf, enc_t, dec_t);
  hipLaunchKernelGGL(attn_kernel, dim3((int)(npix / 256)), dim3(256), 0, stream,
                     q_bf, k_bf, enc_t, W_agg, b_agg, att);
  hipLaunchKernelGGL(conv_out_kernel, dim3(BB * HH), dim3(256), 0, stream,
                     dec_t, packedC, conv_b, att, packedA, b_attn, out);
}

// Round 7
// 152.741 us; speedup vs baseline: 1.5171x; 1.5171x over previous
//
#include <hip/hip_runtime.h>

#define BB 8
#define ENC_C 64
#define DEC_C 128
#define HH 128
#define WW 128

typedef unsigned short ushort_t;
typedef __attribute__((ext_vector_type(8))) short short8;
typedef __attribute__((ext_vector_type(4))) float f32x4;

static __device__ __forceinline__ ushort_t f2bf(float x) {
  unsigned int u = __builtin_bit_cast(unsigned int, x);
  u += 0x7fff + ((u >> 16) & 1);   // round-to-nearest-even
  return (ushort_t)(u >> 16);
}
static __device__ __forceinline__ float bf2f(ushort_t v) {
  unsigned int u = ((unsigned int)v) << 16;
  return __builtin_bit_cast(float, u);
}

// ---------------------------------------------------------------------------
// Kernel 0: pack weight fragments (bf16).
//   blk 0..143   : conv_w (K=1152)  -> packedC
//   blk 144..159 : W_attn (K=128)   -> packedA
//   blk 160..175 : W_dec  (K=128)   -> packedQ
//   blk 176..183 : W_enc  (K=64)    -> packedK
// Frag: lane l, elem j holds W[k = ks*32 + (l>>4)*8 + j][n = nf*16 + (l&15)].
// ---------------------------------------------------------------------------
__global__ __launch_bounds__(64) void pack_w_kernel(
    const float* __restrict__ conv_w, const float* __restrict__ W_attn,
    const float* __restrict__ W_dec, const float* __restrict__ W_enc,
    ushort_t* __restrict__ packedC, ushort_t* __restrict__ packedA,
    ushort_t* __restrict__ packedQ, ushort_t* __restrict__ packedK)
{
  const int blk = blockIdx.x;
  const int l = threadIdx.x;
  const float* W;
  ushort_t* dst;
  int bb;
  if (blk < 144) {
    const int kstep = blk >> 2, nf = blk & 3;
    const int tap = kstep >> 2, dstep = kstep & 3;
    const int n = nf * 16 + (l & 15);
    const int dbase = dstep * 32 + (l >> 4) * 8;
    ushort_t v[8];
    #pragma unroll
    for (int j = 0; j < 8; ++j)
      v[j] = f2bf(conv_w[(tap * DEC_C + dbase + j) * 64 + n]);
    ushort_t* d = packedC + ((long)blk * 64 + l) * 8;
    #pragma unroll
    for (int j = 0; j < 8; ++j) d[j] = v[j];
    return;
  } else if (blk < 160) {
    W = W_attn; dst = packedA; bb = blk - 144;
  } else if (blk < 176) {
    W = W_dec;  dst = packedQ; bb = blk - 160;
  } else {
    W = W_enc;  dst = packedK; bb = blk - 176;
  }
  const int ks = bb >> 2, nf = bb & 3;
  const int n = nf * 16 + (l & 15);
  const int kbase = ks * 32 + (l >> 4) * 8;
  ushort_t v[8];
  #pragma unroll
  for (int j = 0; j < 8; ++j)
    v[j] = f2bf(W[(kbase + j) * 64 + n]);
  ushort_t* d = dst + ((long)bb * 64 + l) * 8;
  #pragma unroll
  for (int j = 0; j < 8; ++j) d[j] = v[j];
}

// ---------------------------------------------------------------------------
// Kernel 1: per (b,h) row. MFMA (A = pixel frags from LDS, B = packed W).
// Outputs q/k NHWC bf16 (+bias), enc_t NHWC bf16, dec_t NHWC bf16.
// NOTE: no waves-per-EU cap — R6 showed a VGPR cap here spills to scratch
// (WRITE_SIZE 225MB vs 84MB ideal).
// ---------------------------------------------------------------------------
__global__ __launch_bounds__(256) void prep_kernel(
    const float* __restrict__ enc, const float* __restrict__ dec,
    const ushort_t* __restrict__ packedQ, const ushort_t* __restrict__ packedK,
    const float* __restrict__ b_enc, const float* __restrict__ b_dec,
    ushort_t* __restrict__ q_nhwc, ushort_t* __restrict__ k_nhwc,
    ushort_t* __restrict__ enc_t, ushort_t* __restrict__ dec_t)
{
  __shared__ float smem[WW * 68];
  const int bh = blockIdx.x;
  const int b = bh >> 7, h = bh & 127;
  const int tid = threadIdx.x;
  const int l = tid & 63;
  const int wv = tid >> 6;
  const int pix0 = wv * 32;
  const int col = l & 15, kg = l >> 4;

  // ---- encoder tile [w][c] f32 ----
  #pragma unroll
  for (int i = 0; i < 32; ++i) {
    int idx = tid + i * 256;
    int cc = idx >> 7, wl = idx & 127;
    smem[wl * 68 + cc] = enc[((b * ENC_C + cc) * HH + h) * WW + wl];
  }
  __syncthreads();

  // enc_t NHWC bf16
  #pragma unroll
  for (int i = 0; i < 32; ++i) {
    int idx = tid + i * 256;
    int wl = idx >> 6, cc = idx & 63;
    enc_t[((long)bh * WW + wl) * 64 + cc] = f2bf(smem[wl * 68 + cc]);
  }

  // k = enc @ W_enc  (A = pixels, D row = pixel -> NHWC)
  f32x4 acck[2][4];
  #pragma unroll
  for (int mf = 0; mf < 2; ++mf)
    #pragma unroll
    for (int nf = 0; nf < 4; ++nf)
      acck[mf][nf] = (f32x4){0.f, 0.f, 0.f, 0.f};

  #pragma unroll
  for (int ks = 0; ks < 2; ++ks) {
    short8 afr[2];
    #pragma unroll
    for (int mf = 0; mf < 2; ++mf) {
      const int pix = pix0 + mf * 16 + col;
      const float4* p = (const float4*)&smem[pix * 68 + ks * 32 + kg * 8];
      float4 x0 = p[0], x1 = p[1];
      short8 v;
      v[0] = (short)f2bf(x0.x); v[1] = (short)f2bf(x0.y);
      v[2] = (short)f2bf(x0.z); v[3] = (short)f2bf(x0.w);
      v[4] = (short)f2bf(x1.x); v[5] = (short)f2bf(x1.y);
      v[6] = (short)f2bf(x1.z); v[7] = (short)f2bf(x1.w);
      afr[mf] = v;
    }
    #pragma unroll
    for (int nf = 0; nf < 4; ++nf) {
      const short8 bfr =
          *(const short8*)(packedK + ((long)(ks * 4 + nf) * 64 + l) * 8);
      acck[0][nf] = __builtin_amdgcn_mfma_f32_16x16x32_bf16(
          afr[0], bfr, acck[0][nf], 0, 0, 0);
      acck[1][nf] = __builtin_amdgcn_mfma_f32_16x16x32_bf16(
          afr[1], bfr, acck[1][nf], 0, 0, 0);
    }
  }
  // store k NHWC bf16
  #pragma unroll
  for (int mf = 0; mf < 2; ++mf)
    #pragma unroll
    for (int nf = 0; nf < 4; ++nf)
      #pragma unroll
      for (int r = 0; r < 4; ++r) {
        const int pix = pix0 + mf * 16 + kg * 4 + r;
        const int c = nf * 16 + col;
        k_nhwc[((long)bh * WW + pix) * 64 + c] = f2bf(acck[mf][nf][r] + b_enc[c]);
      }
  __syncthreads();

  // ---- decoder tile, two 64-channel halves ----
  f32x4 accq[2][4];
  #pragma unroll
  for (int mf = 0; mf < 2; ++mf)
    #pragma unroll
    for (int nf = 0; nf < 4; ++nf)
      accq[mf][nf] = (f32x4){0.f, 0.f, 0.f, 0.f};

  #pragma unroll
  for (int hf = 0; hf < 2; ++hf) {
    #pragma unroll
    for (int i = 0; i < 32; ++i) {
      int idx = tid + i * 256;
      int cc = idx >> 7, wl = idx & 127;
      smem[wl * 68 + cc] = dec[((b * DEC_C + hf * 64 + cc) * HH + h) * WW + wl];
    }
    __syncthreads();

    // dec_t NHWC bf16
    #pragma unroll
    for (int i = 0; i < 32; ++i) {
      int idx = tid + i * 256;
      int wl = idx >> 6, cc = idx & 63;
      dec_t[((long)bh * WW + wl) * DEC_C + hf * 64 + cc] =
          f2bf(smem[wl * 68 + cc]);
    }

    #pragma unroll
    for (int ks2 = 0; ks2 < 2; ++ks2) {
      const int ks = hf * 2 + ks2;
      short8 afr[2];
      #pragma unroll
      for (int mf = 0; mf < 2; ++mf) {
        const int pix = pix0 + mf * 16 + col;
        const float4* p = (const float4*)&smem[pix * 68 + ks2 * 32 + kg * 8];
        float4 x0 = p[0], x1 = p[1];
        short8 v;
        v[0] = (short)f2bf(x0.x); v[1] = (short)f2bf(x0.y);
        v[2] = (short)f2bf(x0.z); v[3] = (short)f2bf(x0.w);
        v[4] = (short)f2bf(x1.x); v[5] = (short)f2bf(x1.y);
        v[6] = (short)f2bf(x1.z); v[7] = (short)f2bf(x1.w);
        afr[mf] = v;
      }
      #pragma unroll
      for (int nf = 0; nf < 4; ++nf) {
        const short8 bfr =
            *(const short8*)(packedQ + ((long)(ks * 4 + nf) * 64 + l) * 8);
        accq[0][nf] = __builtin_amdgcn_mfma_f32_16x16x32_bf16(
            afr[0], bfr, accq[0][nf], 0, 0, 0);
        accq[1][nf] = __builtin_amdgcn_mfma_f32_16x16x32_bf16(
            afr[1], bfr, accq[1][nf], 0, 0, 0);
      }
    }
    __syncthreads();
  }

  // store q NHWC bf16
  #pragma unroll
  for (int mf = 0; mf < 2; ++mf)
    #pragma unroll
    for (int nf = 0; nf < 4; ++nf)
      #pragma unroll
      for (int r = 0; r < 4; ++r) {
        const int pix = pix0 + mf * 16 + kg * 4 + r;
        const int c = nf * 16 + col;
        q_nhwc[((long)bh * WW + pix) * 64 + c] = f2bf(accq[mf][nf][r] + b_dec[c]);
      }
}

// ---------------------------------------------------------------------------
// Kernel 2: attention, thread = pixel, all-NHWC bf16 vector loads.
// ---------------------------------------------------------------------------
__global__ __launch_bounds__(256) void attn_kernel(
    const ushort_t* __restrict__ q_nhwc, const ushort_t* __restrict__ k_nhwc,
    const ushort_t* __restrict__ enc_t, const float* __restrict__ W_agg,
    const float* __restrict__ b_agg, ushort_t* __restrict__ att)
{
  const int nwg = gridDim.x;                 // 512, divisible by 8
  const int cpx = nwg >> 3;
  const int bid = blockIdx.x;
  const int swz = (bid & 7) * cpx + (bid >> 3);   // XCD-contiguous pixels
  const int t = swz * 256 + threadIdx.x;
  const int h = (t >> 7) & 127;
  const int w = t & 127;

  int off[9]; bool valid[9];
  #pragma unroll
  for (int n = 0; n < 9; ++n) {
    const int dh = n / 3 - 1, dw = n % 3 - 1;
    const int nh = h + dh, nw = w + dw;
    valid[n] = (nh >= 0 && nh < HH && nw >= 0 && nw < WW);
    const int nhc = min(max(nh, 0), HH - 1);
    const int nwc = min(max(nw, 0), WW - 1);
    off[n] = (t & ~16383) + nhc * WW + nwc;  // same batch, clamped pixel
  }

  const short8* qp = (const short8*)(q_nhwc + ((long)t << 6));
  const short8* kp[9];
  const short8* ep[9];
  #pragma unroll
  for (int n = 0; n < 9; ++n) {
    kp[n] = (const short8*)(k_nhwc + ((long)off[n] << 6));
    ep[n] = (const short8*)(enc_t + ((long)off[n] << 6));
  }

  // ---- scores: 4 channel-chunks of 16 ----
  float s[9];
  #pragma unroll
  for (int n = 0; n < 9; ++n) s[n] = 0.f;

  for (int ci = 0; ci < 4; ++ci) {        // dynamic: bounds code size
    const short8 qa = qp[2 * ci], qb = qp[2 * ci + 1];
    float wa[16];
    #pragma unroll
    for (int e = 0; e < 16; ++e) wa[e] = W_agg[ci * 16 + e];  // s_load
    #pragma unroll
    for (int n = 0; n < 9; ++n) {
      const short8 ka = kp[n][2 * ci], kb = kp[n][2 * ci + 1];
      float sc = 0.f;
      #pragma unroll
      for (int e = 0; e < 8; ++e) {
        float x = bf2f((ushort_t)qa[e]) + bf2f((ushort_t)ka[e]);
        x = fminf(fmaxf(x, -15.f), 15.f);
        float z = __builtin_amdgcn_exp2f(x * 2.88539008f);
        float tt = __builtin_fmaf(-2.f, __builtin_amdgcn_rcpf(z + 1.f), 1.f);
        sc = __builtin_fmaf(tt, wa[e], sc);
      }
      #pragma unroll
      for (int e = 0; e < 8; ++e) {
        float x = bf2f((ushort_t)qb[e]) + bf2f((ushort_t)kb[e]);
        x = fminf(fmaxf(x, -15.f), 15.f);
        float z = __builtin_amdgcn_exp2f(x * 2.88539008f);
        float tt = __builtin_fmaf(-2.f, __builtin_amdgcn_rcpf(z + 1.f), 1.f);
        sc = __builtin_fmaf(tt, wa[8 + e], sc);
      }
      s[n] += sc;
    }
  }

  // ---- masked softmax ----
  const float bagg = b_agg[0];
  float m = -1e30f;
  #pragma unroll
  for (int n = 0; n < 9; ++n) {
    s[n] = valid[n] ? (s[n] + bagg) : -1e30f;
    m = fmaxf(m, s[n]);
  }
  float attw[9]; float denom = 0.f;
  #pragma unroll
  for (int n = 0; n < 9; ++n) {
    attw[n] = __builtin_amdgcn_exp2f((s[n] - m) * 1.44269504f);
    denom += attw[n];
  }
  const float inv = __builtin_amdgcn_rcpf(denom);
  #pragma unroll
  for (int n = 0; n < 9; ++n) attw[n] *= inv;   // invalid -> exactly 0

  // ---- weighted encoder sum, chunked; contiguous 128B/lane store ----
  short8* op = (short8*)(att + ((long)t << 6));
  for (int ci = 0; ci < 4; ++ci) {
    float a16[16];
    #pragma unroll
    for (int e = 0; e < 16; ++e) a16[e] = 0.f;
    #pragma unroll
    for (int n = 0; n < 9; ++n) {
      const short8 ea = ep[n][2 * ci], eb = ep[n][2 * ci + 1];
      #pragma unroll
      for (int e = 0; e < 8; ++e)
        a16[e] = __builtin_fmaf(attw[n], bf2f((ushort_t)ea[e]), a16[e]);
      #pragma unroll
      for (int e = 0; e < 8; ++e)
        a16[8 + e] = __builtin_fmaf(attw[n], bf2f((ushort_t)eb[e]), a16[8 + e]);
    }
    short8 o0, o1;
    #pragma unroll
    for (int e = 0; e < 8; ++e) {
      o0[e] = (short)f2bf(a16[e]);
      o1[e] = (short)f2bf(a16[8 + e]);
    }
    op[2 * ci] = o0;
    op[2 * ci + 1] = o1;
  }
}

// ---------------------------------------------------------------------------
// Kernel 3: fused conv(3x3 MFMA) + out = LeakyReLU([vals;attn]@W_attn + b).
// XCD swizzle: h-adjacent blocks share dec_t rows in one XCD's L2.
// ---------------------------------------------------------------------------
__global__ __launch_bounds__(256) void conv_out_kernel(
    const ushort_t* __restrict__ dec_t, const ushort_t* __restrict__ packedC,
    const float* __restrict__ conv_b, const ushort_t* __restrict__ attn_nhwc,
    const ushort_t* __restrict__ packedA, const float* __restrict__ b_attn,
    float* __restrict__ out)
{
  __shared__ ushort_t vlds[WW * 68];
  const int nwg = gridDim.x;                 // 1024, divisible by 8
  const int cpx = nwg >> 3;
  const int bid = blockIdx.x;
  const int bh = (bid & 7) * cpx + (bid >> 3);
  const int b = bh >> 7, h = bh & 127;
  const int tid = threadIdx.x;
  const int l = tid & 63;
  const int wv = tid >> 6;
  const int pix0 = wv * 32;
  const int col = l & 15, kg = l >> 4;

  // ---- conv phase ----
  f32x4 acc[2][4];
  #pragma unroll
  for (int mf = 0; mf < 2; ++mf)
    #pragma unroll
    for (int nf = 0; nf < 4; ++nf)
      acc[mf][nf] = (f32x4){0.f, 0.f, 0.f, 0.f};

  #pragma unroll
  for (int kh = 0; kh < 3; ++kh) {
    const int hh = h + kh - 1;
    if (hh < 0 || hh >= HH) continue;   // block-uniform skip
    const ushort_t* arow = dec_t + ((long)(b * HH + hh) * WW) * DEC_C;
    #pragma unroll
    for (int ds = 0; ds < 4; ++ds) {
      const int d0 = ds * 32;
      // hoist all 6 A-frags (3 kw x 2 mf) for this (kh, ds)
      short8 afr[3][2];
      #pragma unroll
      for (int kw = 0; kw < 3; ++kw)
        #pragma unroll
        for (int mf = 0; mf < 2; ++mf) {
          const int wp = pix0 + mf * 16 + col + kw - 1;
          short8 v = {0, 0, 0, 0, 0, 0, 0, 0};
          if (wp >= 0 && wp < WW)
            v = *(const short8*)(arow + (long)wp * DEC_C + d0 + kg * 8);
          afr[kw][mf] = v;
        }
      #pragma unroll
      for (int kw = 0; kw < 3; ++kw) {
        const int kstep = (kh * 3 + kw) * 4 + ds;
        #pragma unroll
        for (int nf = 0; nf < 4; ++nf) {
          const short8 bfr =
              *(const short8*)(packedC + ((long)(kstep * 4 + nf) * 64 + l) * 8);
          acc[0][nf] = __builtin_amdgcn_mfma_f32_16x16x32_bf16(
              afr[kw][0], bfr, acc[0][nf], 0, 0, 0);
          acc[1][nf] = __builtin_amdgcn_mfma_f32_16x16x32_bf16(
              afr[kw][1], bfr, acc[1][nf], 0, 0, 0);
        }
      }
    }
  }

  // vals -> LDS bf16 [pix][c] stride 68
  #pragma unroll
  for (int mf = 0; mf < 2; ++mf)
    #pragma unroll
    for (int nf = 0; nf < 4; ++nf)
      #pragma unroll
      for (int r = 0; r < 4; ++r) {
        const int pix = pix0 + mf * 16 + kg * 4 + r;
        const int c = nf * 16 + col;
        vlds[pix * 68 + c] = f2bf(acc[mf][nf][r] + conv_b[c]);
      }
  __syncthreads();

  // ---- out phase (swapped: A = W_attn frags, B = cat^T; D = (ch, pix)) ----
  f32x4 ao[4][2];
  #pragma unroll
  for (int mf = 0; mf < 4; ++mf)
    #pragma unroll
    for (int pf = 0; pf < 2; ++pf)
      ao[mf][pf] = (f32x4){0.f, 0.f, 0.f, 0.f};

  #pragma unroll
  for (int ks = 0; ks < 4; ++ks) {
    short8 bfr[2];
    #pragma unroll
    for (int pf = 0; pf < 2; ++pf) {
      const int pix = pix0 + pf * 16 + col;
      short8 v;
      if (ks < 2) {
        const int k0 = ks * 32 + kg * 8;
        #pragma unroll
        for (int e = 0; e < 8; ++e) v[e] = (short)vlds[pix * 68 + k0 + e];
      } else {
        v = *(const short8*)(attn_nhwc + ((long)bh * WW + pix) * 64 +
                             (ks - 2) * 32 + kg * 8);
      }
      bfr[pf] = v;
    }
    #pragma unroll
    for (int mf = 0; mf < 4; ++mf) {
      const short8 afr =
          *(const short8*)(packedA + ((long)(ks * 4 + mf) * 64 + l) * 8);
      #pragma unroll
      for (int pf = 0; pf < 2; ++pf)
        ao[mf][pf] = __builtin_amdgcn_mfma_f32_16x16x32_bf16(
            afr, bfr[pf], ao[mf][pf], 0, 0, 0);
    }
  }

  // direct NCHW f32 stores
  #pragma unroll
  for (int mf = 0; mf < 4; ++mf)
    #pragma unroll
    for (int pf = 0; pf < 2; ++pf)
      #pragma unroll
      for (int r = 0; r < 4; ++r) {
        const int n = mf * 16 + kg * 4 + r;
        const int pix = pix0 + pf * 16 + col;
        float o = ao[mf][pf][r] + b_attn[n];
        o = (o >= 0.f) ? o : 0.2f * o;
        out[((long)(b * ENC_C + n) * HH + h) * WW + pix] = o;
      }
}

// ---------------------------------------------------------------------------
extern "C" void kernel_launch(void* const* d_in, const int* in_sizes, int n_in,
                              void* d_out, int out_size, void* d_ws, size_t ws_size,
                              hipStream_t stream) {
  const float* enc    = (const float*)d_in[0];
  const float* dec    = (const float*)d_in[1];
  const float* W_enc  = (const float*)d_in[2];
  const float* b_enc  = (const float*)d_in[3];
  const float* W_dec  = (const float*)d_in[4];
  const float* b_dec  = (const float*)d_in[5];
  const float* W_agg  = (const float*)d_in[6];
  const float* b_agg  = (const float*)d_in[7];
  const float* W_attn = (const float*)d_in[8];
  const float* b_attn = (const float*)d_in[9];
  const float* conv_w = (const float*)d_in[10];
  const float* conv_b = (const float*)d_in[11];
  float* out = (float*)d_out;

  const long npix = (long)BB * HH * WW;               // 131072
  ushort_t* q_bf    = (ushort_t*)d_ws;                // [npix][64] bf16 NHWC
  ushort_t* k_bf    = q_bf + npix * 64;               // [npix][64]
  ushort_t* enc_t   = k_bf + npix * 64;               // [npix][64]
  ushort_t* dec_t   = enc_t + npix * 64;              // [npix][128]
  ushort_t* att     = dec_t + npix * 128;             // [npix][64]
  ushort_t* packedC = att + npix * 64;                // conv W frags
  ushort_t* packedA = packedC + 144 * 64 * 8;
  ushort_t* packedQ = packedA + 16 * 64 * 8;
  ushort_t* packedK = packedQ + 16 * 64 * 8;

  hipLaunchKernelGGL(pack_w_kernel, dim3(184), dim3(64), 0, stream,
                     conv_w, W_attn, W_dec, W_enc, packedC, packedA, packedQ, packedK);
  hipLaunchKernelGGL(prep_kernel, dim3(BB * HH), dim3(256), 0, stream,
                     enc, dec, packedQ, packedK, b_enc, b_dec, q_bf, k_bf, enc_t, dec_t);
  hipLaunchKernelGGL(attn_kernel, dim3((int)(npix / 256)), dim3(256), 0, stream,
                     q_bf, k_bf, enc_t, W_agg, b_agg, att);
  hipLaunchKernelGGL(conv_out_kernel, dim3(BB * HH), dim3(256), 0, stream,
                     dec_t, packedC, conv_b, att, packedA, b_attn, out);
}

// Round 8
// 146.865 us; speedup vs baseline: 1.5778x; 1.0400x over previous
//
#include <hip/hip_runtime.h>

#define BB 8
#define ENC_C 64
#define DEC_C 128
#define HH 128
#define WW 128

typedef unsigned short ushort_t;
typedef __attribute__((ext_vector_type(8))) short short8;
typedef __attribute__((ext_vector_type(4))) float f32x4;

static __device__ __forceinline__ ushort_t f2bf(float x) {
  unsigned int u = __builtin_bit_cast(unsigned int, x);
  u += 0x7fff + ((u >> 16) & 1);   // round-to-nearest-even
  return (ushort_t)(u >> 16);
}
static __device__ __forceinline__ float bf2f(ushort_t v) {
  unsigned int u = ((unsigned int)v) << 16;
  return __builtin_bit_cast(float, u);
}

// ---------------------------------------------------------------------------
// Kernel 0: pack weight fragments (bf16).
//   blk 0..143   : conv_w (K=1152)  -> packedC
//   blk 144..159 : W_attn (K=128)   -> packedA
//   blk 160..175 : W_dec  (K=128)   -> packedQ
//   blk 176..183 : W_enc  (K=64)    -> packedK
// Frag: lane l, elem j holds W[k = ks*32 + (l>>4)*8 + j][n = nf*16 + (l&15)].
// ---------------------------------------------------------------------------
__global__ __launch_bounds__(64) void pack_w_kernel(
    const float* __restrict__ conv_w, const float* __restrict__ W_attn,
    const float* __restrict__ W_dec, const float* __restrict__ W_enc,
    ushort_t* __restrict__ packedC, ushort_t* __restrict__ packedA,
    ushort_t* __restrict__ packedQ, ushort_t* __restrict__ packedK)
{
  const int blk = blockIdx.x;
  const int l = threadIdx.x;
  const float* W;
  ushort_t* dst;
  int bb;
  if (blk < 144) {
    const int kstep = blk >> 2, nf = blk & 3;
    const int tap = kstep >> 2, dstep = kstep & 3;
    const int n = nf * 16 + (l & 15);
    const int dbase = dstep * 32 + (l >> 4) * 8;
    ushort_t v[8];
    #pragma unroll
    for (int j = 0; j < 8; ++j)
      v[j] = f2bf(conv_w[(tap * DEC_C + dbase + j) * 64 + n]);
    ushort_t* d = packedC + ((long)blk * 64 + l) * 8;
    #pragma unroll
    for (int j = 0; j < 8; ++j) d[j] = v[j];
    return;
  } else if (blk < 160) {
    W = W_attn; dst = packedA; bb = blk - 144;
  } else if (blk < 176) {
    W = W_dec;  dst = packedQ; bb = blk - 160;
  } else {
    W = W_enc;  dst = packedK; bb = blk - 176;
  }
  const int ks = bb >> 2, nf = bb & 3;
  const int n = nf * 16 + (l & 15);
  const int kbase = ks * 32 + (l >> 4) * 8;
  ushort_t v[8];
  #pragma unroll
  for (int j = 0; j < 8; ++j)
    v[j] = f2bf(W[(kbase + j) * 64 + n]);
  ushort_t* d = dst + ((long)bb * 64 + l) * 8;
  #pragma unroll
  for (int j = 0; j < 8; ++j) d[j] = v[j];
}

// ---------------------------------------------------------------------------
// Kernel 1: per (b,h) row. MFMA (A = pixel frags from LDS, B = packed W).
// Outputs q/k NHWC bf16 (+bias), enc_t NHWC bf16, dec_t NHWC bf16.
// No waves-per-EU cap: R6 showed a VGPR cap here spills to scratch.
// ---------------------------------------------------------------------------
__global__ __launch_bounds__(256) void prep_kernel(
    const float* __restrict__ enc, const float* __restrict__ dec,
    const ushort_t* __restrict__ packedQ, const ushort_t* __restrict__ packedK,
    const float* __restrict__ b_enc, const float* __restrict__ b_dec,
    ushort_t* __restrict__ q_nhwc, ushort_t* __restrict__ k_nhwc,
    ushort_t* __restrict__ enc_t, ushort_t* __restrict__ dec_t)
{
  __shared__ float smem[WW * 68];
  const int bh = blockIdx.x;
  const int b = bh >> 7, h = bh & 127;
  const int tid = threadIdx.x;
  const int l = tid & 63;
  const int wv = tid >> 6;
  const int pix0 = wv * 32;
  const int col = l & 15, kg = l >> 4;

  // ---- encoder tile [w][c] f32 ----
  #pragma unroll
  for (int i = 0; i < 32; ++i) {
    int idx = tid + i * 256;
    int cc = idx >> 7, wl = idx & 127;
    smem[wl * 68 + cc] = enc[((b * ENC_C + cc) * HH + h) * WW + wl];
  }
  __syncthreads();

  // enc_t NHWC bf16
  #pragma unroll
  for (int i = 0; i < 32; ++i) {
    int idx = tid + i * 256;
    int wl = idx >> 6, cc = idx & 63;
    enc_t[((long)bh * WW + wl) * 64 + cc] = f2bf(smem[wl * 68 + cc]);
  }

  // k = enc @ W_enc  (A = pixels, D row = pixel -> NHWC)
  f32x4 acck[2][4];
  #pragma unroll
  for (int mf = 0; mf < 2; ++mf)
    #pragma unroll
    for (int nf = 0; nf < 4; ++nf)
      acck[mf][nf] = (f32x4){0.f, 0.f, 0.f, 0.f};

  #pragma unroll
  for (int ks = 0; ks < 2; ++ks) {
    short8 afr[2];
    #pragma unroll
    for (int mf = 0; mf < 2; ++mf) {
      const int pix = pix0 + mf * 16 + col;
      const float4* p = (const float4*)&smem[pix * 68 + ks * 32 + kg * 8];
      float4 x0 = p[0], x1 = p[1];
      short8 v;
      v[0] = (short)f2bf(x0.x); v[1] = (short)f2bf(x0.y);
      v[2] = (short)f2bf(x0.z); v[3] = (short)f2bf(x0.w);
      v[4] = (short)f2bf(x1.x); v[5] = (short)f2bf(x1.y);
      v[6] = (short)f2bf(x1.z); v[7] = (short)f2bf(x1.w);
      afr[mf] = v;
    }
    #pragma unroll
    for (int nf = 0; nf < 4; ++nf) {
      const short8 bfr =
          *(const short8*)(packedK + ((long)(ks * 4 + nf) * 64 + l) * 8);
      acck[0][nf] = __builtin_amdgcn_mfma_f32_16x16x32_bf16(
          afr[0], bfr, acck[0][nf], 0, 0, 0);
      acck[1][nf] = __builtin_amdgcn_mfma_f32_16x16x32_bf16(
          afr[1], bfr, acck[1][nf], 0, 0, 0);
    }
  }
  // store k NHWC bf16
  #pragma unroll
  for (int mf = 0; mf < 2; ++mf)
    #pragma unroll
    for (int nf = 0; nf < 4; ++nf)
      #pragma unroll
      for (int r = 0; r < 4; ++r) {
        const int pix = pix0 + mf * 16 + kg * 4 + r;
        const int c = nf * 16 + col;
        k_nhwc[((long)bh * WW + pix) * 64 + c] = f2bf(acck[mf][nf][r] + b_enc[c]);
      }
  __syncthreads();

  // ---- decoder tile, two 64-channel halves ----
  f32x4 accq[2][4];
  #pragma unroll
  for (int mf = 0; mf < 2; ++mf)
    #pragma unroll
    for (int nf = 0; nf < 4; ++nf)
      accq[mf][nf] = (f32x4){0.f, 0.f, 0.f, 0.f};

  #pragma unroll
  for (int hf = 0; hf < 2; ++hf) {
    #pragma unroll
    for (int i = 0; i < 32; ++i) {
      int idx = tid + i * 256;
      int cc = idx >> 7, wl = idx & 127;
      smem[wl * 68 + cc] = dec[((b * DEC_C + hf * 64 + cc) * HH + h) * WW + wl];
    }
    __syncthreads();

    // dec_t NHWC bf16
    #pragma unroll
    for (int i = 0; i < 32; ++i) {
      int idx = tid + i * 256;
      int wl = idx >> 6, cc = idx & 63;
      dec_t[((long)bh * WW + wl) * DEC_C + hf * 64 + cc] =
          f2bf(smem[wl * 68 + cc]);
    }

    #pragma unroll
    for (int ks2 = 0; ks2 < 2; ++ks2) {
      const int ks = hf * 2 + ks2;
      short8 afr[2];
      #pragma unroll
      for (int mf = 0; mf < 2; ++mf) {
        const int pix = pix0 + mf * 16 + col;
        const float4* p = (const float4*)&smem[pix * 68 + ks2 * 32 + kg * 8];
        float4 x0 = p[0], x1 = p[1];
        short8 v;
        v[0] = (short)f2bf(x0.x); v[1] = (short)f2bf(x0.y);
        v[2] = (short)f2bf(x0.z); v[3] = (short)f2bf(x0.w);
        v[4] = (short)f2bf(x1.x); v[5] = (short)f2bf(x1.y);
        v[6] = (short)f2bf(x1.z); v[7] = (short)f2bf(x1.w);
        afr[mf] = v;
      }
      #pragma unroll
      for (int nf = 0; nf < 4; ++nf) {
        const short8 bfr =
            *(const short8*)(packedQ + ((long)(ks * 4 + nf) * 64 + l) * 8);
        accq[0][nf] = __builtin_amdgcn_mfma_f32_16x16x32_bf16(
            afr[0], bfr, accq[0][nf], 0, 0, 0);
        accq[1][nf] = __builtin_amdgcn_mfma_f32_16x16x32_bf16(
            afr[1], bfr, accq[1][nf], 0, 0, 0);
      }
    }
    __syncthreads();
  }

  // store q NHWC bf16
  #pragma unroll
  for (int mf = 0; mf < 2; ++mf)
    #pragma unroll
    for (int nf = 0; nf < 4; ++nf)
      #pragma unroll
      for (int r = 0; r < 4; ++r) {
        const int pix = pix0 + mf * 16 + kg * 4 + r;
        const int c = nf * 16 + col;
        q_nhwc[((long)bh * WW + pix) * 64 + c] = f2bf(accq[mf][nf][r] + b_dec[c]);
      }
}

// ---------------------------------------------------------------------------
// Kernel 2: attention, thread = pixel, all-NHWC bf16 vector loads.
// ---------------------------------------------------------------------------
__global__ __launch_bounds__(256) void attn_kernel(
    const ushort_t* __restrict__ q_nhwc, const ushort_t* __restrict__ k_nhwc,
    const ushort_t* __restrict__ enc_t, const float* __restrict__ W_agg,
    const float* __restrict__ b_agg, ushort_t* __restrict__ att)
{
  const int nwg = gridDim.x;                 // 512, divisible by 8
  const int cpx = nwg >> 3;
  const int bid = blockIdx.x;
  const int swz = (bid & 7) * cpx + (bid >> 3);   // XCD-contiguous pixels
  const int t = swz * 256 + threadIdx.x;
  const int h = (t >> 7) & 127;
  const int w = t & 127;

  int off[9]; bool valid[9];
  #pragma unroll
  for (int n = 0; n < 9; ++n) {
    const int dh = n / 3 - 1, dw = n % 3 - 1;
    const int nh = h + dh, nw = w + dw;
    valid[n] = (nh >= 0 && nh < HH && nw >= 0 && nw < WW);
    const int nhc = min(max(nh, 0), HH - 1);
    const int nwc = min(max(nw, 0), WW - 1);
    off[n] = (t & ~16383) + nhc * WW + nwc;  // same batch, clamped pixel
  }

  const short8* qp = (const short8*)(q_nhwc + ((long)t << 6));
  const short8* kp[9];
  const short8* ep[9];
  #pragma unroll
  for (int n = 0; n < 9; ++n) {
    kp[n] = (const short8*)(k_nhwc + ((long)off[n] << 6));
    ep[n] = (const short8*)(enc_t + ((long)off[n] << 6));
  }

  // ---- scores: 4 channel-chunks of 16 ----
  float s[9];
  #pragma unroll
  for (int n = 0; n < 9; ++n) s[n] = 0.f;

  for (int ci = 0; ci < 4; ++ci) {        // dynamic: bounds code size
    const short8 qa = qp[2 * ci], qb = qp[2 * ci + 1];
    float wa[16];
    #pragma unroll
    for (int e = 0; e < 16; ++e) wa[e] = W_agg[ci * 16 + e];  // s_load
    #pragma unroll
    for (int n = 0; n < 9; ++n) {
      const short8 ka = kp[n][2 * ci], kb = kp[n][2 * ci + 1];
      float sc = 0.f;
      #pragma unroll
      for (int e = 0; e < 8; ++e) {
        float x = bf2f((ushort_t)qa[e]) + bf2f((ushort_t)ka[e]);
        x = fminf(fmaxf(x, -15.f), 15.f);
        float z = __builtin_amdgcn_exp2f(x * 2.88539008f);
        float tt = __builtin_fmaf(-2.f, __builtin_amdgcn_rcpf(z + 1.f), 1.f);
        sc = __builtin_fmaf(tt, wa[e], sc);
      }
      #pragma unroll
      for (int e = 0; e < 8; ++e) {
        float x = bf2f((ushort_t)qb[e]) + bf2f((ushort_t)kb[e]);
        x = fminf(fmaxf(x, -15.f), 15.f);
        float z = __builtin_amdgcn_exp2f(x * 2.88539008f);
        float tt = __builtin_fmaf(-2.f, __builtin_amdgcn_rcpf(z + 1.f), 1.f);
        sc = __builtin_fmaf(tt, wa[8 + e], sc);
      }
      s[n] += sc;
    }
  }

  // ---- masked softmax ----
  const float bagg = b_agg[0];
  float m = -1e30f;
  #pragma unroll
  for (int n = 0; n < 9; ++n) {
    s[n] = valid[n] ? (s[n] + bagg) : -1e30f;
    m = fmaxf(m, s[n]);
  }
  float attw[9]; float denom = 0.f;
  #pragma unroll
  for (int n = 0; n < 9; ++n) {
    attw[n] = __builtin_amdgcn_exp2f((s[n] - m) * 1.44269504f);
    denom += attw[n];
  }
  const float inv = __builtin_amdgcn_rcpf(denom);
  #pragma unroll
  for (int n = 0; n < 9; ++n) attw[n] *= inv;   // invalid -> exactly 0

  // ---- weighted encoder sum, chunked; contiguous 128B/lane store ----
  short8* op = (short8*)(att + ((long)t << 6));
  for (int ci = 0; ci < 4; ++ci) {
    float a16[16];
    #pragma unroll
    for (int e = 0; e < 16; ++e) a16[e] = 0.f;
    #pragma unroll
    for (int n = 0; n < 9; ++n) {
      const short8 ea = ep[n][2 * ci], eb = ep[n][2 * ci + 1];
      #pragma unroll
      for (int e = 0; e < 8; ++e)
        a16[e] = __builtin_fmaf(attw[n], bf2f((ushort_t)ea[e]), a16[e]);
      #pragma unroll
      for (int e = 0; e < 8; ++e)
        a16[8 + e] = __builtin_fmaf(attw[n], bf2f((ushort_t)eb[e]), a16[8 + e]);
    }
    short8 o0, o1;
    #pragma unroll
    for (int e = 0; e < 8; ++e) {
      o0[e] = (short)f2bf(a16[e]);
      o1[e] = (short)f2bf(a16[8 + e]);
    }
    op[2 * ci] = o0;
    op[2 * ci + 1] = o1;
  }
}

// ---------------------------------------------------------------------------
// Kernel 3: fused conv(3x3 MFMA) + out = LeakyReLU([vals;attn]@W_attn + b).
// NEW: per-kh 48KB LDS staging of packedC (block-cooperative) — B-frag L2
// traffic /4 per CU, MFMA feeds from short-latency ds_read_b128.
// LDS 48KB -> 3 blocks/CU; (256,3) matches that occupancy (VGPR cap ~170).
// ---------------------------------------------------------------------------
__global__ __launch_bounds__(256, 3) void conv_out_kernel(
    const ushort_t* __restrict__ dec_t, const ushort_t* __restrict__ packedC,
    const float* __restrict__ conv_b, const ushort_t* __restrict__ attn_nhwc,
    const ushort_t* __restrict__ packedA, const float* __restrict__ b_attn,
    float* __restrict__ out)
{
  __shared__ ushort_t bsh[24576];            // 48 KB: one kh slice (48 frags)
  ushort_t* vlds = bsh;                      // out-phase alias, stride 72
  const int nwg = gridDim.x;                 // 1024, divisible by 8
  const int cpx = nwg >> 3;
  const int bid = blockIdx.x;
  const int bh = (bid & 7) * cpx + (bid >> 3);
  const int b = bh >> 7, h = bh & 127;
  const int tid = threadIdx.x;
  const int l = tid & 63;
  const int wv = tid >> 6;
  const int pix0 = wv * 32;
  const int col = l & 15, kg = l >> 4;

  // ---- conv phase ----
  f32x4 acc[2][4];
  #pragma unroll
  for (int mf = 0; mf < 2; ++mf)
    #pragma unroll
    for (int nf = 0; nf < 4; ++nf)
      acc[mf][nf] = (f32x4){0.f, 0.f, 0.f, 0.f};

  #pragma unroll
  for (int kh = 0; kh < 3; ++kh) {
    const int hh = h + kh - 1;
    if (hh < 0 || hh >= HH) continue;        // block-uniform skip
    // stage this kh's 48 frags (48 KB) into LDS, coalesced
    __syncthreads();                          // prior slice's reads done
    {
      const short8* src = (const short8*)(packedC + (long)kh * 24576);
      #pragma unroll
      for (int i = 0; i < 12; ++i)
        *(short8*)&bsh[(tid + i * 256) * 8] = src[tid + i * 256];
    }
    __syncthreads();

    const ushort_t* arow = dec_t + ((long)(b * HH + hh) * WW) * DEC_C;
    #pragma unroll
    for (int ds = 0; ds < 4; ++ds) {
      const int d0 = ds * 32;
      // hoist all 6 A-frags (3 kw x 2 mf) for this (kh, ds)
      short8 afr[3][2];
      #pragma unroll
      for (int kw = 0; kw < 3; ++kw)
        #pragma unroll
        for (int mf = 0; mf < 2; ++mf) {
          const int wp = pix0 + mf * 16 + col + kw - 1;
          short8 v = {0, 0, 0, 0, 0, 0, 0, 0};
          if (wp >= 0 && wp < WW)
            v = *(const short8*)(arow + (long)wp * DEC_C + d0 + kg * 8);
          afr[kw][mf] = v;
        }
      #pragma unroll
      for (int kw = 0; kw < 3; ++kw) {
        #pragma unroll
        for (int nf = 0; nf < 4; ++nf) {
          const short8 bfr =
              *(const short8*)&bsh[(((kw * 4 + ds) * 4 + nf) * 64 + l) * 8];
          acc[0][nf] = __builtin_amdgcn_mfma_f32_16x16x32_bf16(
              afr[kw][0], bfr, acc[0][nf], 0, 0, 0);
          acc[1][nf] = __builtin_amdgcn_mfma_f32_16x16x32_bf16(
              afr[kw][1], bfr, acc[1][nf], 0, 0, 0);
        }
      }
    }
  }

  // vals -> LDS bf16 [pix][c] stride 72 (16B-aligned rows)
  __syncthreads();                            // last slice's B reads done
  #pragma unroll
  for (int mf = 0; mf < 2; ++mf)
    #pragma unroll
    for (int nf = 0; nf < 4; ++nf)
      #pragma unroll
      for (int r = 0; r < 4; ++r) {
        const int pix = pix0 + mf * 16 + kg * 4 + r;
        const int c = nf * 16 + col;
        vlds[pix * 72 + c] = f2bf(acc[mf][nf][r] + conv_b[c]);
      }
  __syncthreads();

  // ---- out phase (swapped: A = W_attn frags, B = cat^T; D = (ch, pix)) ----
  f32x4 ao[4][2];
  #pragma unroll
  for (int mf = 0; mf < 4; ++mf)
    #pragma unroll
    for (int pf = 0; pf < 2; ++pf)
      ao[mf][pf] = (f32x4){0.f, 0.f, 0.f, 0.f};

  #pragma unroll
  for (int ks = 0; ks < 4; ++ks) {
    short8 bfr[2];
    #pragma unroll
    for (int pf = 0; pf < 2; ++pf) {
      const int pix = pix0 + pf * 16 + col;
      short8 v;
      if (ks < 2) {
        v = *(const short8*)&vlds[pix * 72 + ks * 32 + kg * 8];  // b128
      } else {
        v = *(const short8*)(attn_nhwc + ((long)bh * WW + pix) * 64 +
                             (ks - 2) * 32 + kg * 8);
      }
      bfr[pf] = v;
    }
    #pragma unroll
    for (int mf = 0; mf < 4; ++mf) {
      const short8 afr =
          *(const short8*)(packedA + ((long)(ks * 4 + mf) * 64 + l) * 8);
      #pragma unroll
      for (int pf = 0; pf < 2; ++pf)
        ao[mf][pf] = __builtin_amdgcn_mfma_f32_16x16x32_bf16(
            afr, bfr[pf], ao[mf][pf], 0, 0, 0);
    }
  }

  // direct NCHW f32 stores
  #pragma unroll
  for (int mf = 0; mf < 4; ++mf)
    #pragma unroll
    for (int pf = 0; pf < 2; ++pf)
      #pragma unroll
      for (int r = 0; r < 4; ++r) {
        const int n = mf * 16 + kg * 4 + r;
        const int pix = pix0 + pf * 16 + col;
        float o = ao[mf][pf][r] + b_attn[n];
        o = (o >= 0.f) ? o : 0.2f * o;
        out[((long)(b * ENC_C + n) * HH + h) * WW + pix] = o;
      }
}

// ---------------------------------------------------------------------------
extern "C" void kernel_launch(void* const* d_in, const int* in_sizes, int n_in,
                              void* d_out, int out_size, void* d_ws, size_t ws_size,
                              hipStream_t stream) {
  const float* enc    = (const float*)d_in[0];
  const float* dec    = (const float*)d_in[1];
  const float* W_enc  = (const float*)d_in[2];
  const float* b_enc  = (const float*)d_in[3];
  const float* W_dec  = (const float*)d_in[4];
  const float* b_dec  = (const float*)d_in[5];
  const float* W_agg  = (const float*)d_in[6];
  const float* b_agg  = (const float*)d_in[7];
  const float* W_attn = (const float*)d_in[8];
  const float* b_attn = (const float*)d_in[9];
  const float* conv_w = (const float*)d_in[10];
  const float* conv_b = (const float*)d_in[11];
  float* out = (float*)d_out;

  const long npix = (long)BB * HH * WW;               // 131072
  ushort_t* q_bf    = (ushort_t*)d_ws;                // [npix][64] bf16 NHWC
  ushort_t* k_bf    = q_bf + npix * 64;               // [npix][64]
  ushort_t* enc_t   = k_bf + npix * 64;               // [npix][64]
  ushort_t* dec_t   = enc_t + npix * 64;              // [npix][128]
  ushort_t* att     = dec_t + npix * 128;             // [npix][64]
  ushort_t* packedC = att + npix * 64;                // conv W frags
  ushort_t* packedA = packedC + 144 * 64 * 8;
  ushort_t* packedQ = packedA + 16 * 64 * 8;
  ushort_t* packedK = packedQ + 16 * 64 * 8;

  hipLaunchKernelGGL(pack_w_kernel, dim3(184), dim3(64), 0, stream,
                     conv_w, W_attn, W_dec, W_enc, packedC, packedA, packedQ, packedK);
  hipLaunchKernelGGL(prep_kernel, dim3(BB * HH), dim3(256), 0, stream,
                     enc, dec, packedQ, packedK, b_enc, b_dec, q_bf, k_bf, enc_t, dec_t);
  hipLaunchKernelGGL(attn_kernel, dim3((int)(npix / 256)), dim3(256), 0, stream,
                     q_bf, k_bf, enc_t, W_agg, b_agg, att);
  hipLaunchKernelGGL(conv_out_kernel, dim3(BB * HH), dim3(256), 0, stream,
                     dec_t, packedC, conv_b, att, packedA, b_attn, out);
}

// Round 9
// 145.668 us; speedup vs baseline: 1.5908x; 1.0082x over previous
//
#include <hip/hip_runtime.h>

#define BB 8
#define ENC_C 64
#define DEC_C 128
#define HH 128
#define WW 128

typedef unsigned short ushort_t;
typedef __attribute__((ext_vector_type(8))) short short8;
typedef __attribute__((ext_vector_type(4))) float f32x4;

static __device__ __forceinline__ ushort_t f2bf(float x) {
  unsigned int u = __builtin_bit_cast(unsigned int, x);
  u += 0x7fff + ((u >> 16) & 1);   // round-to-nearest-even
  return (ushort_t)(u >> 16);
}
static __device__ __forceinline__ float bf2f(ushort_t v) {
  unsigned int u = ((unsigned int)v) << 16;
  return __builtin_bit_cast(float, u);
}

// ---------------------------------------------------------------------------
// Kernel 0: pack weight fragments (bf16).
//   blk 0..143   : conv_w (K=1152)  -> packedC
//   blk 144..159 : W_attn (K=128)   -> packedA
//   blk 160..175 : W_dec  (K=128)   -> packedQ
//   blk 176..183 : W_enc  (K=64)    -> packedK
// Frag: lane l, elem j holds W[k = ks*32 + (l>>4)*8 + j][n = nf*16 + (l&15)].
// ---------------------------------------------------------------------------
__global__ __launch_bounds__(64) void pack_w_kernel(
    const float* __restrict__ conv_w, const float* __restrict__ W_attn,
    const float* __restrict__ W_dec, const float* __restrict__ W_enc,
    ushort_t* __restrict__ packedC, ushort_t* __restrict__ packedA,
    ushort_t* __restrict__ packedQ, ushort_t* __restrict__ packedK)
{
  const int blk = blockIdx.x;
  const int l = threadIdx.x;
  const float* W;
  ushort_t* dst;
  int bb;
  if (blk < 144) {
    const int kstep = blk >> 2, nf = blk & 3;
    const int tap = kstep >> 2, dstep = kstep & 3;
    const int n = nf * 16 + (l & 15);
    const int dbase = dstep * 32 + (l >> 4) * 8;
    ushort_t v[8];
    #pragma unroll
    for (int j = 0; j < 8; ++j)
      v[j] = f2bf(conv_w[(tap * DEC_C + dbase + j) * 64 + n]);
    ushort_t* d = packedC + ((long)blk * 64 + l) * 8;
    #pragma unroll
    for (int j = 0; j < 8; ++j) d[j] = v[j];
    return;
  } else if (blk < 160) {
    W = W_attn; dst = packedA; bb = blk - 144;
  } else if (blk < 176) {
    W = W_dec;  dst = packedQ; bb = blk - 160;
  } else {
    W = W_enc;  dst = packedK; bb = blk - 176;
  }
  const int ks = bb >> 2, nf = bb & 3;
  const int n = nf * 16 + (l & 15);
  const int kbase = ks * 32 + (l >> 4) * 8;
  ushort_t v[8];
  #pragma unroll
  for (int j = 0; j < 8; ++j)
    v[j] = f2bf(W[(kbase + j) * 64 + n]);
  ushort_t* d = dst + ((long)bb * 64 + l) * 8;
  #pragma unroll
  for (int j = 0; j < 8; ++j) d[j] = v[j];
}

// ---------------------------------------------------------------------------
// Kernel 1: per (b,h) row. MFMA (A = pixel frags from LDS, B = packed W).
// Outputs q/k NHWC bf16 (+bias), enc_t NHWC bf16, dec_t NHWC bf16.
// No waves-per-EU cap: R6 showed a VGPR cap here spills to scratch.
// ---------------------------------------------------------------------------
__global__ __launch_bounds__(256) void prep_kernel(
    const float* __restrict__ enc, const float* __restrict__ dec,
    const ushort_t* __restrict__ packedQ, const ushort_t* __restrict__ packedK,
    const float* __restrict__ b_enc, const float* __restrict__ b_dec,
    ushort_t* __restrict__ q_nhwc, ushort_t* __restrict__ k_nhwc,
    ushort_t* __restrict__ enc_t, ushort_t* __restrict__ dec_t)
{
  __shared__ float smem[WW * 68];
  const int bh = blockIdx.x;
  const int b = bh >> 7, h = bh & 127;
  const int tid = threadIdx.x;
  const int l = tid & 63;
  const int wv = tid >> 6;
  const int pix0 = wv * 32;
  const int col = l & 15, kg = l >> 4;

  // ---- encoder tile [w][c] f32 ----
  #pragma unroll
  for (int i = 0; i < 32; ++i) {
    int idx = tid + i * 256;
    int cc = idx >> 7, wl = idx & 127;
    smem[wl * 68 + cc] = enc[((b * ENC_C + cc) * HH + h) * WW + wl];
  }
  __syncthreads();

  // enc_t NHWC bf16
  #pragma unroll
  for (int i = 0; i < 32; ++i) {
    int idx = tid + i * 256;
    int wl = idx >> 6, cc = idx & 63;
    enc_t[((long)bh * WW + wl) * 64 + cc] = f2bf(smem[wl * 68 + cc]);
  }

  // k = enc @ W_enc  (A = pixels, D row = pixel -> NHWC)
  f32x4 acck[2][4];
  #pragma unroll
  for (int mf = 0; mf < 2; ++mf)
    #pragma unroll
    for (int nf = 0; nf < 4; ++nf)
      acck[mf][nf] = (f32x4){0.f, 0.f, 0.f, 0.f};

  #pragma unroll
  for (int ks = 0; ks < 2; ++ks) {
    short8 afr[2];
    #pragma unroll
    for (int mf = 0; mf < 2; ++mf) {
      const int pix = pix0 + mf * 16 + col;
      const float4* p = (const float4*)&smem[pix * 68 + ks * 32 + kg * 8];
      float4 x0 = p[0], x1 = p[1];
      short8 v;
      v[0] = (short)f2bf(x0.x); v[1] = (short)f2bf(x0.y);
      v[2] = (short)f2bf(x0.z); v[3] = (short)f2bf(x0.w);
      v[4] = (short)f2bf(x1.x); v[5] = (short)f2bf(x1.y);
      v[6] = (short)f2bf(x1.z); v[7] = (short)f2bf(x1.w);
      afr[mf] = v;
    }
    #pragma unroll
    for (int nf = 0; nf < 4; ++nf) {
      const short8 bfr =
          *(const short8*)(packedK + ((long)(ks * 4 + nf) * 64 + l) * 8);
      acck[0][nf] = __builtin_amdgcn_mfma_f32_16x16x32_bf16(
          afr[0], bfr, acck[0][nf], 0, 0, 0);
      acck[1][nf] = __builtin_amdgcn_mfma_f32_16x16x32_bf16(
          afr[1], bfr, acck[1][nf], 0, 0, 0);
    }
  }
  // store k NHWC bf16
  #pragma unroll
  for (int mf = 0; mf < 2; ++mf)
    #pragma unroll
    for (int nf = 0; nf < 4; ++nf)
      #pragma unroll
      for (int r = 0; r < 4; ++r) {
        const int pix = pix0 + mf * 16 + kg * 4 + r;
        const int c = nf * 16 + col;
        k_nhwc[((long)bh * WW + pix) * 64 + c] = f2bf(acck[mf][nf][r] + b_enc[c]);
      }
  __syncthreads();

  // ---- decoder tile, two 64-channel halves ----
  f32x4 accq[2][4];
  #pragma unroll
  for (int mf = 0; mf < 2; ++mf)
    #pragma unroll
    for (int nf = 0; nf < 4; ++nf)
      accq[mf][nf] = (f32x4){0.f, 0.f, 0.f, 0.f};

  #pragma unroll
  for (int hf = 0; hf < 2; ++hf) {
    #pragma unroll
    for (int i = 0; i < 32; ++i) {
      int idx = tid + i * 256;
      int cc = idx >> 7, wl = idx & 127;
      smem[wl * 68 + cc] = dec[((b * DEC_C + hf * 64 + cc) * HH + h) * WW + wl];
    }
    __syncthreads();

    // dec_t NHWC bf16
    #pragma unroll
    for (int i = 0; i < 32; ++i) {
      int idx = tid + i * 256;
      int wl = idx >> 6, cc = idx & 63;
      dec_t[((long)bh * WW + wl) * DEC_C + hf * 64 + cc] =
          f2bf(smem[wl * 68 + cc]);
    }

    #pragma unroll
    for (int ks2 = 0; ks2 < 2; ++ks2) {
      const int ks = hf * 2 + ks2;
      short8 afr[2];
      #pragma unroll
      for (int mf = 0; mf < 2; ++mf) {
        const int pix = pix0 + mf * 16 + col;
        const float4* p = (const float4*)&smem[pix * 68 + ks2 * 32 + kg * 8];
        float4 x0 = p[0], x1 = p[1];
        short8 v;
        v[0] = (short)f2bf(x0.x); v[1] = (short)f2bf(x0.y);
        v[2] = (short)f2bf(x0.z); v[3] = (short)f2bf(x0.w);
        v[4] = (short)f2bf(x1.x); v[5] = (short)f2bf(x1.y);
        v[6] = (short)f2bf(x1.z); v[7] = (short)f2bf(x1.w);
        afr[mf] = v;
      }
      #pragma unroll
      for (int nf = 0; nf < 4; ++nf) {
        const short8 bfr =
            *(const short8*)(packedQ + ((long)(ks * 4 + nf) * 64 + l) * 8);
        accq[0][nf] = __builtin_amdgcn_mfma_f32_16x16x32_bf16(
            afr[0], bfr, accq[0][nf], 0, 0, 0);
        accq[1][nf] = __builtin_amdgcn_mfma_f32_16x16x32_bf16(
            afr[1], bfr, accq[1][nf], 0, 0, 0);
      }
    }
    __syncthreads();
  }

  // store q NHWC bf16
  #pragma unroll
  for (int mf = 0; mf < 2; ++mf)
    #pragma unroll
    for (int nf = 0; nf < 4; ++nf)
      #pragma unroll
      for (int r = 0; r < 4; ++r) {
        const int pix = pix0 + mf * 16 + kg * 4 + r;
        const int c = nf * 16 + col;
        q_nhwc[((long)bh * WW + pix) * 64 + c] = f2bf(accq[mf][nf][r] + b_dec[c]);
      }
}

// ---------------------------------------------------------------------------
// Kernel 2: attention, thread = pixel, all-NHWC bf16 vector loads.
// ---------------------------------------------------------------------------
__global__ __launch_bounds__(256) void attn_kernel(
    const ushort_t* __restrict__ q_nhwc, const ushort_t* __restrict__ k_nhwc,
    const ushort_t* __restrict__ enc_t, const float* __restrict__ W_agg,
    const float* __restrict__ b_agg, ushort_t* __restrict__ att)
{
  const int nwg = gridDim.x;                 // 512, divisible by 8
  const int cpx = nwg >> 3;
  const int bid = blockIdx.x;
  const int swz = (bid & 7) * cpx + (bid >> 3);   // XCD-contiguous pixels
  const int t = swz * 256 + threadIdx.x;
  const int h = (t >> 7) & 127;
  const int w = t & 127;

  int off[9]; bool valid[9];
  #pragma unroll
  for (int n = 0; n < 9; ++n) {
    const int dh = n / 3 - 1, dw = n % 3 - 1;
    const int nh = h + dh, nw = w + dw;
    valid[n] = (nh >= 0 && nh < HH && nw >= 0 && nw < WW);
    const int nhc = min(max(nh, 0), HH - 1);
    const int nwc = min(max(nw, 0), WW - 1);
    off[n] = (t & ~16383) + nhc * WW + nwc;  // same batch, clamped pixel
  }

  const short8* qp = (const short8*)(q_nhwc + ((long)t << 6));
  const short8* kp[9];
  const short8* ep[9];
  #pragma unroll
  for (int n = 0; n < 9; ++n) {
    kp[n] = (const short8*)(k_nhwc + ((long)off[n] << 6));
    ep[n] = (const short8*)(enc_t + ((long)off[n] << 6));
  }

  // ---- scores: 4 channel-chunks of 16 ----
  float s[9];
  #pragma unroll
  for (int n = 0; n < 9; ++n) s[n] = 0.f;

  for (int ci = 0; ci < 4; ++ci) {        // dynamic: bounds code size
    const short8 qa = qp[2 * ci], qb = qp[2 * ci + 1];
    float wa[16];
    #pragma unroll
    for (int e = 0; e < 16; ++e) wa[e] = W_agg[ci * 16 + e];  // s_load
    #pragma unroll
    for (int n = 0; n < 9; ++n) {
      const short8 ka = kp[n][2 * ci], kb = kp[n][2 * ci + 1];
      float sc = 0.f;
      #pragma unroll
      for (int e = 0; e < 8; ++e) {
        float x = bf2f((ushort_t)qa[e]) + bf2f((ushort_t)ka[e]);
        x = fminf(fmaxf(x, -15.f), 15.f);
        float z = __builtin_amdgcn_exp2f(x * 2.88539008f);
        float tt = __builtin_fmaf(-2.f, __builtin_amdgcn_rcpf(z + 1.f), 1.f);
        sc = __builtin_fmaf(tt, wa[e], sc);
      }
      #pragma unroll
      for (int e = 0; e < 8; ++e) {
        float x = bf2f((ushort_t)qb[e]) + bf2f((ushort_t)kb[e]);
        x = fminf(fmaxf(x, -15.f), 15.f);
        float z = __builtin_amdgcn_exp2f(x * 2.88539008f);
        float tt = __builtin_fmaf(-2.f, __builtin_amdgcn_rcpf(z + 1.f), 1.f);
        sc = __builtin_fmaf(tt, wa[8 + e], sc);
      }
      s[n] += sc;
    }
  }

  // ---- masked softmax ----
  const float bagg = b_agg[0];
  float m = -1e30f;
  #pragma unroll
  for (int n = 0; n < 9; ++n) {
    s[n] = valid[n] ? (s[n] + bagg) : -1e30f;
    m = fmaxf(m, s[n]);
  }
  float attw[9]; float denom = 0.f;
  #pragma unroll
  for (int n = 0; n < 9; ++n) {
    attw[n] = __builtin_amdgcn_exp2f((s[n] - m) * 1.44269504f);
    denom += attw[n];
  }
  const float inv = __builtin_amdgcn_rcpf(denom);
  #pragma unroll
  for (int n = 0; n < 9; ++n) attw[n] *= inv;   // invalid -> exactly 0

  // ---- weighted encoder sum, chunked; contiguous 128B/lane store ----
  short8* op = (short8*)(att + ((long)t << 6));
  for (int ci = 0; ci < 4; ++ci) {
    float a16[16];
    #pragma unroll
    for (int e = 0; e < 16; ++e) a16[e] = 0.f;
    #pragma unroll
    for (int n = 0; n < 9; ++n) {
      const short8 ea = ep[n][2 * ci], eb = ep[n][2 * ci + 1];
      #pragma unroll
      for (int e = 0; e < 8; ++e)
        a16[e] = __builtin_fmaf(attw[n], bf2f((ushort_t)ea[e]), a16[e]);
      #pragma unroll
      for (int e = 0; e < 8; ++e)
        a16[8 + e] = __builtin_fmaf(attw[n], bf2f((ushort_t)eb[e]), a16[8 + e]);
    }
    short8 o0, o1;
    #pragma unroll
    for (int e = 0; e < 8; ++e) {
      o0[e] = (short)f2bf(a16[e]);
      o1[e] = (short)f2bf(a16[8 + e]);
    }
    op[2 * ci] = o0;
    op[2 * ci + 1] = o1;
  }
}

// ---------------------------------------------------------------------------
// Kernel 3: fused conv(3x3 MFMA) + out, TWO rows per block (grid 512).
// Per-kh 48KB staged packedC feeds both rows (4 MFMAs per ds_read);
// two independent accumulation chains per wave double schedulable ILP.
// Zero-pad semantics: OOB rows/pixels contribute zero A-frags.
// ---------------------------------------------------------------------------
__global__ __launch_bounds__(256) void conv_out_kernel(
    const ushort_t* __restrict__ dec_t, const ushort_t* __restrict__ packedC,
    const float* __restrict__ conv_b, const ushort_t* __restrict__ attn_nhwc,
    const ushort_t* __restrict__ packedA, const float* __restrict__ b_attn,
    float* __restrict__ out)
{
  __shared__ ushort_t bsh[24576];            // 48 KB: one kh slice (48 frags)
  ushort_t* vlds = bsh;                      // out-phase alias: 2 rows, stride 72
  const int nwg = gridDim.x;                 // 512, divisible by 8
  const int cpx = nwg >> 3;
  const int bid = blockIdx.x;
  const int grp = (bid & 7) * cpx + (bid >> 3);
  const int b = grp >> 6;                    // 64 row-pairs per batch
  const int h0 = (grp & 63) * 2;
  const int tid = threadIdx.x;
  const int l = tid & 63;
  const int wv = tid >> 6;
  const int pix0 = wv * 32;
  const int col = l & 15, kg = l >> 4;

  // ---- conv phase: acc[row][mf][nf] ----
  f32x4 acc[2][2][4];
  #pragma unroll
  for (int r = 0; r < 2; ++r)
    #pragma unroll
    for (int mf = 0; mf < 2; ++mf)
      #pragma unroll
      for (int nf = 0; nf < 4; ++nf)
        acc[r][mf][nf] = (f32x4){0.f, 0.f, 0.f, 0.f};

  #pragma unroll
  for (int kh = 0; kh < 3; ++kh) {
    // stage this kh's 48 frags (48 KB) into LDS, coalesced
    __syncthreads();                          // prior slice's reads done
    {
      const short8* src = (const short8*)(packedC + (long)kh * 24576);
      #pragma unroll
      for (int i = 0; i < 12; ++i)
        *(short8*)&bsh[(tid + i * 256) * 8] = src[tid + i * 256];
    }
    __syncthreads();

    const int hh0 = h0 + kh - 1;              // input row for r=0
    const bool v0 = (hh0 >= 0);               // h0 even, h0+kh <= 128
    const bool v1 = (h0 + kh <= HH - 1);      // input row for r=1 is hh0+1
    const ushort_t* arow0 = dec_t + ((long)(b * HH + (v0 ? hh0 : 0)) * WW) * DEC_C;
    const ushort_t* arow1 = dec_t + ((long)(b * HH + (v1 ? hh0 + 1 : 0)) * WW) * DEC_C;

    #pragma unroll
    for (int ds = 0; ds < 4; ++ds) {
      const int d0 = ds * 32;
      short8 afr[2][3][2];                    // [row][kw][mf]
      #pragma unroll
      for (int kw = 0; kw < 3; ++kw)
        #pragma unroll
        for (int mf = 0; mf < 2; ++mf) {
          const int wp = pix0 + mf * 16 + col + kw - 1;
          const bool wok = (wp >= 0 && wp < WW);
          short8 z = {0, 0, 0, 0, 0, 0, 0, 0};
          afr[0][kw][mf] = (wok && v0)
              ? *(const short8*)(arow0 + (long)wp * DEC_C + d0 + kg * 8) : z;
          afr[1][kw][mf] = (wok && v1)
              ? *(const short8*)(arow1 + (long)wp * DEC_C + d0 + kg * 8) : z;
        }
      #pragma unroll
      for (int kw = 0; kw < 3; ++kw) {
        #pragma unroll
        for (int nf = 0; nf < 4; ++nf) {
          const short8 bfr =
              *(const short8*)&bsh[(((kw * 4 + ds) * 4 + nf) * 64 + l) * 8];
          #pragma unroll
          for (int r = 0; r < 2; ++r) {
            acc[r][0][nf] = __builtin_amdgcn_mfma_f32_16x16x32_bf16(
                afr[r][kw][0], bfr, acc[r][0][nf], 0, 0, 0);
            acc[r][1][nf] = __builtin_amdgcn_mfma_f32_16x16x32_bf16(
                afr[r][kw][1], bfr, acc[r][1][nf], 0, 0, 0);
          }
        }
      }
    }
  }

  // vals -> LDS bf16 [row*128+pix][c] stride 72 (16B-aligned rows)
  __syncthreads();                            // last slice's B reads done
  #pragma unroll
  for (int r = 0; r < 2; ++r)
    #pragma unroll
    for (int mf = 0; mf < 2; ++mf)
      #pragma unroll
      for (int nf = 0; nf < 4; ++nf)
        #pragma unroll
        for (int rr = 0; rr < 4; ++rr) {
          const int pix = pix0 + mf * 16 + kg * 4 + rr;
          const int c = nf * 16 + col;
          vlds[(r * WW + pix) * 72 + c] = f2bf(acc[r][mf][nf][rr] + conv_b[c]);
        }
  __syncthreads();

  // ---- out phase (swapped: A = W_attn frags, B = cat^T; D = (ch, pix)) ----
  for (int r = 0; r < 2; ++r) {
    const int bh = b * HH + h0 + r;
    f32x4 ao[4][2];
    #pragma unroll
    for (int mf = 0; mf < 4; ++mf)
      #pragma unroll
      for (int pf = 0; pf < 2; ++pf)
        ao[mf][pf] = (f32x4){0.f, 0.f, 0.f, 0.f};

    #pragma unroll
    for (int ks = 0; ks < 4; ++ks) {
      short8 bfr[2];
      #pragma unroll
      for (int pf = 0; pf < 2; ++pf) {
        const int pix = pix0 + pf * 16 + col;
        short8 v;
        if (ks < 2) {
          v = *(const short8*)&vlds[(r * WW + pix) * 72 + ks * 32 + kg * 8];
        } else {
          v = *(const short8*)(attn_nhwc + ((long)bh * WW + pix) * 64 +
                               (ks - 2) * 32 + kg * 8);
        }
        bfr[pf] = v;
      }
      #pragma unroll
      for (int mf = 0; mf < 4; ++mf) {
        const short8 afr =
            *(const short8*)(packedA + ((long)(ks * 4 + mf) * 64 + l) * 8);
        #pragma unroll
        for (int pf = 0; pf < 2; ++pf)
          ao[mf][pf] = __builtin_amdgcn_mfma_f32_16x16x32_bf16(
              afr, bfr[pf], ao[mf][pf], 0, 0, 0);
      }
    }

    // direct NCHW f32 stores
    #pragma unroll
    for (int mf = 0; mf < 4; ++mf)
      #pragma unroll
      for (int pf = 0; pf < 2; ++pf)
        #pragma unroll
        for (int rr = 0; rr < 4; ++rr) {
          const int n = mf * 16 + kg * 4 + rr;
          const int pix = pix0 + pf * 16 + col;
          float o = ao[mf][pf][rr] + b_attn[n];
          o = (o >= 0.f) ? o : 0.2f * o;
          out[((long)(b * ENC_C + n) * HH + (h0 + r)) * WW + pix] = o;
        }
  }
}

// ---------------------------------------------------------------------------
extern "C" void kernel_launch(void* const* d_in, const int* in_sizes, int n_in,
                              void* d_out, int out_size, void* d_ws, size_t ws_size,
                              hipStream_t stream) {
  const float* enc    = (const float*)d_in[0];
  const float* dec    = (const float*)d_in[1];
  const float* W_enc  = (const float*)d_in[2];
  const float* b_enc  = (const float*)d_in[3];
  const float* W_dec  = (const float*)d_in[4];
  const float* b_dec  = (const float*)d_in[5];
  const float* W_agg  = (const float*)d_in[6];
  const float* b_agg  = (const float*)d_in[7];
  const float* W_attn = (const float*)d_in[8];
  const float* b_attn = (const float*)d_in[9];
  const float* conv_w = (const float*)d_in[10];
  const float* conv_b = (const float*)d_in[11];
  float* out = (float*)d_out;

  const long npix = (long)BB * HH * WW;               // 131072
  ushort_t* q_bf    = (ushort_t*)d_ws;                // [npix][64] bf16 NHWC
  ushort_t* k_bf    = q_bf + npix * 64;               // [npix][64]
  ushort_t* enc_t   = k_bf + npix * 64;               // [npix][64]
  ushort_t* dec_t   = enc_t + npix * 64;              // [npix][128]
  ushort_t* att     = dec_t + npix * 128;             // [npix][64]
  ushort_t* packedC = att + npix * 64;                // conv W frags
  ushort_t* packedA = packedC + 144 * 64 * 8;
  ushort_t* packedQ = packedA + 16 * 64 * 8;
  ushort_t* packedK = packedQ + 16 * 64 * 8;

  hipLaunchKernelGGL(pack_w_kernel, dim3(184), dim3(64), 0, stream,
                     conv_w, W_attn, W_dec, W_enc, packedC, packedA, packedQ, packedK);
  hipLaunchKernelGGL(prep_kernel, dim3(BB * HH), dim3(256), 0, stream,
                     enc, dec, packedQ, packedK, b_enc, b_dec, q_bf, k_bf, enc_t, dec_t);
  hipLaunchKernelGGL(attn_kernel, dim3((int)(npix / 256)), dim3(256), 0, stream,
                     q_bf, k_bf, enc_t, W_agg, b_agg, att);
  hipLaunchKernelGGL(conv_out_kernel, dim3(BB * HH / 2), dim3(256), 0, stream,
                     dec_t, packedC, conv_b, att, packedA, b_attn, out);
}

// Round 10
// 123.009 us; speedup vs baseline: 1.8838x; 1.1842x over previous
//
#include <hip/hip_runtime.h>

#define BB 8
#define ENC_C 64
#define DEC_C 128
#define HH 128
#define WW 128

typedef unsigned short ushort_t;
typedef __attribute__((ext_vector_type(8))) short short8;
typedef __attribute__((ext_vector_type(4))) float f32x4;

static __device__ __forceinline__ ushort_t f2bf(float x) {
  unsigned int u = __builtin_bit_cast(unsigned int, x);
  u += 0x7fff + ((u >> 16) & 1);   // round-to-nearest-even
  return (ushort_t)(u >> 16);
}
static __device__ __forceinline__ float bf2f(ushort_t v) {
  unsigned int u = ((unsigned int)v) << 16;
  return __builtin_bit_cast(float, u);
}

// ---------------------------------------------------------------------------
// Kernel 0: pack weight fragments (bf16).
//   blk 0..143   : conv_w (K=1152)  -> packedC
//   blk 144..159 : W_attn (K=128)   -> packedA
//   blk 160..175 : W_dec  (K=128)   -> packedQ
//   blk 176..183 : W_enc  (K=64)    -> packedK
// Frag: lane l, elem j holds W[k = ks*32 + (l>>4)*8 + j][n = nf*16 + (l&15)].
// ---------------------------------------------------------------------------
__global__ __launch_bounds__(64) void pack_w_kernel(
    const float* __restrict__ conv_w, const float* __restrict__ W_attn,
    const float* __restrict__ W_dec, const float* __restrict__ W_enc,
    ushort_t* __restrict__ packedC, ushort_t* __restrict__ packedA,
    ushort_t* __restrict__ packedQ, ushort_t* __restrict__ packedK)
{
  const int blk = blockIdx.x;
  const int l = threadIdx.x;
  const float* W;
  ushort_t* dst;
  int bb;
  if (blk < 144) {
    const int kstep = blk >> 2, nf = blk & 3;
    const int tap = kstep >> 2, dstep = kstep & 3;
    const int n = nf * 16 + (l & 15);
    const int dbase = dstep * 32 + (l >> 4) * 8;
    ushort_t v[8];
    #pragma unroll
    for (int j = 0; j < 8; ++j)
      v[j] = f2bf(conv_w[(tap * DEC_C + dbase + j) * 64 + n]);
    ushort_t* d = packedC + ((long)blk * 64 + l) * 8;
    #pragma unroll
    for (int j = 0; j < 8; ++j) d[j] = v[j];
    return;
  } else if (blk < 160) {
    W = W_attn; dst = packedA; bb = blk - 144;
  } else if (blk < 176) {
    W = W_dec;  dst = packedQ; bb = blk - 160;
  } else {
    W = W_enc;  dst = packedK; bb = blk - 176;
  }
  const int ks = bb >> 2, nf = bb & 3;
  const int n = nf * 16 + (l & 15);
  const int kbase = ks * 32 + (l >> 4) * 8;
  ushort_t v[8];
  #pragma unroll
  for (int j = 0; j < 8; ++j)
    v[j] = f2bf(W[(kbase + j) * 64 + n]);
  ushort_t* d = dst + ((long)bb * 64 + l) * 8;
  #pragma unroll
  for (int j = 0; j < 8; ++j) d[j] = v[j];
}

// ---------------------------------------------------------------------------
// Kernel 1: per (b,h) row. MFMA (A = pixel frags from LDS, B = packed W).
// Outputs q/k NHWC bf16 (+bias), enc_t NHWC bf16, dec_t NHWC bf16.
// No waves-per-EU cap: R6 showed a VGPR cap here spills to scratch.
// ---------------------------------------------------------------------------
__global__ __launch_bounds__(256) void prep_kernel(
    const float* __restrict__ enc, const float* __restrict__ dec,
    const ushort_t* __restrict__ packedQ, const ushort_t* __restrict__ packedK,
    const float* __restrict__ b_enc, const float* __restrict__ b_dec,
    ushort_t* __restrict__ q_nhwc, ushort_t* __restrict__ k_nhwc,
    ushort_t* __restrict__ enc_t, ushort_t* __restrict__ dec_t)
{
  __shared__ float smem[WW * 68];
  const int bh = blockIdx.x;
  const int b = bh >> 7, h = bh & 127;
  const int tid = threadIdx.x;
  const int l = tid & 63;
  const int wv = tid >> 6;
  const int pix0 = wv * 32;
  const int col = l & 15, kg = l >> 4;

  // ---- encoder tile [w][c] f32 ----
  #pragma unroll
  for (int i = 0; i < 32; ++i) {
    int idx = tid + i * 256;
    int cc = idx >> 7, wl = idx & 127;
    smem[wl * 68 + cc] = enc[((b * ENC_C + cc) * HH + h) * WW + wl];
  }
  __syncthreads();

  // enc_t NHWC bf16
  #pragma unroll
  for (int i = 0; i < 32; ++i) {
    int idx = tid + i * 256;
    int wl = idx >> 6, cc = idx & 63;
    enc_t[((long)bh * WW + wl) * 64 + cc] = f2bf(smem[wl * 68 + cc]);
  }

  // k = enc @ W_enc  (A = pixels, D row = pixel -> NHWC)
  f32x4 acck[2][4];
  #pragma unroll
  for (int mf = 0; mf < 2; ++mf)
    #pragma unroll
    for (int nf = 0; nf < 4; ++nf)
      acck[mf][nf] = (f32x4){0.f, 0.f, 0.f, 0.f};

  #pragma unroll
  for (int ks = 0; ks < 2; ++ks) {
    short8 afr[2];
    #pragma unroll
    for (int mf = 0; mf < 2; ++mf) {
      const int pix = pix0 + mf * 16 + col;
      const float4* p = (const float4*)&smem[pix * 68 + ks * 32 + kg * 8];
      float4 x0 = p[0], x1 = p[1];
      short8 v;
      v[0] = (short)f2bf(x0.x); v[1] = (short)f2bf(x0.y);
      v[2] = (short)f2bf(x0.z); v[3] = (short)f2bf(x0.w);
      v[4] = (short)f2bf(x1.x); v[5] = (short)f2bf(x1.y);
      v[6] = (short)f2bf(x1.z); v[7] = (short)f2bf(x1.w);
      afr[mf] = v;
    }
    #pragma unroll
    for (int nf = 0; nf < 4; ++nf) {
      const short8 bfr =
          *(const short8*)(packedK + ((long)(ks * 4 + nf) * 64 + l) * 8);
      acck[0][nf] = __builtin_amdgcn_mfma_f32_16x16x32_bf16(
          afr[0], bfr, acck[0][nf], 0, 0, 0);
      acck[1][nf] = __builtin_amdgcn_mfma_f32_16x16x32_bf16(
          afr[1], bfr, acck[1][nf], 0, 0, 0);
    }
  }
  // store k NHWC bf16
  #pragma unroll
  for (int mf = 0; mf < 2; ++mf)
    #pragma unroll
    for (int nf = 0; nf < 4; ++nf)
      #pragma unroll
      for (int r = 0; r < 4; ++r) {
        const int pix = pix0 + mf * 16 + kg * 4 + r;
        const int c = nf * 16 + col;
        k_nhwc[((long)bh * WW + pix) * 64 + c] = f2bf(acck[mf][nf][r] + b_enc[c]);
      }
  __syncthreads();

  // ---- decoder tile, two 64-channel halves ----
  f32x4 accq[2][4];
  #pragma unroll
  for (int mf = 0; mf < 2; ++mf)
    #pragma unroll
    for (int nf = 0; nf < 4; ++nf)
      accq[mf][nf] = (f32x4){0.f, 0.f, 0.f, 0.f};

  #pragma unroll
  for (int hf = 0; hf < 2; ++hf) {
    #pragma unroll
    for (int i = 0; i < 32; ++i) {
      int idx = tid + i * 256;
      int cc = idx >> 7, wl = idx & 127;
      smem[wl * 68 + cc] = dec[((b * DEC_C + hf * 64 + cc) * HH + h) * WW + wl];
    }
    __syncthreads();

    // dec_t NHWC bf16
    #pragma unroll
    for (int i = 0; i < 32; ++i) {
      int idx = tid + i * 256;
      int wl = idx >> 6, cc = idx & 63;
      dec_t[((long)bh * WW + wl) * DEC_C + hf * 64 + cc] =
          f2bf(smem[wl * 68 + cc]);
    }

    #pragma unroll
    for (int ks2 = 0; ks2 < 2; ++ks2) {
      const int ks = hf * 2 + ks2;
      short8 afr[2];
      #pragma unroll
      for (int mf = 0; mf < 2; ++mf) {
        const int pix = pix0 + mf * 16 + col;
        const float4* p = (const float4*)&smem[pix * 68 + ks2 * 32 + kg * 8];
        float4 x0 = p[0], x1 = p[1];
        short8 v;
        v[0] = (short)f2bf(x0.x); v[1] = (short)f2bf(x0.y);
        v[2] = (short)f2bf(x0.z); v[3] = (short)f2bf(x0.w);
        v[4] = (short)f2bf(x1.x); v[5] = (short)f2bf(x1.y);
        v[6] = (short)f2bf(x1.z); v[7] = (short)f2bf(x1.w);
        afr[mf] = v;
      }
      #pragma unroll
      for (int nf = 0; nf < 4; ++nf) {
        const short8 bfr =
            *(const short8*)(packedQ + ((long)(ks * 4 + nf) * 64 + l) * 8);
        accq[0][nf] = __builtin_amdgcn_mfma_f32_16x16x32_bf16(
            afr[0], bfr, accq[0][nf], 0, 0, 0);
        accq[1][nf] = __builtin_amdgcn_mfma_f32_16x16x32_bf16(
            afr[1], bfr, accq[1][nf], 0, 0, 0);
      }
    }
    __syncthreads();
  }

  // store q NHWC bf16
  #pragma unroll
  for (int mf = 0; mf < 2; ++mf)
    #pragma unroll
    for (int nf = 0; nf < 4; ++nf)
      #pragma unroll
      for (int r = 0; r < 4; ++r) {
        const int pix = pix0 + mf * 16 + kg * 4 + r;
        const int c = nf * 16 + col;
        q_nhwc[((long)bh * WW + pix) * 64 + c] = f2bf(accq[mf][nf][r] + b_dec[c]);
      }
}

// ---------------------------------------------------------------------------
// Kernel 2: attention, FOUR threads per pixel (16 channels each).
// Score partials combined via 2x shfl_xor (lanes 0-3 = one pixel);
// softmax duplicated per lane; weighted sum + store channel-split.
// Grid 2048 -> 8 blocks/CU (was 2) for latency hiding.
// ---------------------------------------------------------------------------
__global__ __launch_bounds__(256) void attn_kernel(
    const ushort_t* __restrict__ q_nhwc, const ushort_t* __restrict__ k_nhwc,
    const ushort_t* __restrict__ enc_t, const float* __restrict__ W_agg,
    const float* __restrict__ b_agg, ushort_t* __restrict__ att)
{
  const int nwg = gridDim.x;                 // 2048, divisible by 8
  const int cpx = nwg >> 3;
  const int bid = blockIdx.x;
  const int swz = (bid & 7) * cpx + (bid >> 3);   // XCD-contiguous pixels
  const int t = swz * 256 + threadIdx.x;     // 0 .. 4*npix-1
  const int pix = t >> 2;
  const int cb = (t & 3) * 16;               // this thread's channel base
  const int h = (pix >> 7) & 127;
  const int w = pix & 127;

  int off[9]; bool valid[9];
  #pragma unroll
  for (int n = 0; n < 9; ++n) {
    const int dh = n / 3 - 1, dw = n % 3 - 1;
    const int nh = h + dh, nw = w + dw;
    valid[n] = (nh >= 0 && nh < HH && nw >= 0 && nw < WW);
    const int nhc = min(max(nh, 0), HH - 1);
    const int nwc = min(max(nw, 0), WW - 1);
    off[n] = (pix & ~16383) + nhc * WW + nwc;  // same batch, clamped pixel
  }

  const short8* qp = (const short8*)(q_nhwc + ((long)pix << 6) + cb);
  const short8 qa = qp[0], qb = qp[1];

  float wa[16];
  {
    float4 w0 = *(const float4*)(W_agg + cb);
    float4 w1 = *(const float4*)(W_agg + cb + 4);
    float4 w2 = *(const float4*)(W_agg + cb + 8);
    float4 w3 = *(const float4*)(W_agg + cb + 12);
    wa[0]=w0.x; wa[1]=w0.y; wa[2]=w0.z; wa[3]=w0.w;
    wa[4]=w1.x; wa[5]=w1.y; wa[6]=w1.z; wa[7]=w1.w;
    wa[8]=w2.x; wa[9]=w2.y; wa[10]=w2.z; wa[11]=w2.w;
    wa[12]=w3.x; wa[13]=w3.y; wa[14]=w3.z; wa[15]=w3.w;
  }

  // ---- score partials over this thread's 16 channels ----
  float s[9];
  #pragma unroll
  for (int n = 0; n < 9; ++n) {
    const short8* kp = (const short8*)(k_nhwc + ((long)off[n] << 6) + cb);
    const short8 ka = kp[0], kb = kp[1];
    float sc = 0.f;
    #pragma unroll
    for (int e = 0; e < 8; ++e) {
      float x = bf2f((ushort_t)qa[e]) + bf2f((ushort_t)ka[e]);
      x = fminf(fmaxf(x, -15.f), 15.f);
      float z = __builtin_amdgcn_exp2f(x * 2.88539008f);
      float tt = __builtin_fmaf(-2.f, __builtin_amdgcn_rcpf(z + 1.f), 1.f);
      sc = __builtin_fmaf(tt, wa[e], sc);
    }
    #pragma unroll
    for (int e = 0; e < 8; ++e) {
      float x = bf2f((ushort_t)qb[e]) + bf2f((ushort_t)kb[e]);
      x = fminf(fmaxf(x, -15.f), 15.f);
      float z = __builtin_amdgcn_exp2f(x * 2.88539008f);
      float tt = __builtin_fmaf(-2.f, __builtin_amdgcn_rcpf(z + 1.f), 1.f);
      sc = __builtin_fmaf(tt, wa[8 + e], sc);
    }
    s[n] = sc;
  }

  // ---- combine partials across the 4 lanes of this pixel ----
  #pragma unroll
  for (int n = 0; n < 9; ++n) {
    s[n] += __shfl_xor(s[n], 1);
    s[n] += __shfl_xor(s[n], 2);
  }

  // ---- masked softmax (duplicated in all 4 lanes) ----
  const float bagg = b_agg[0];
  float m = -1e30f;
  #pragma unroll
  for (int n = 0; n < 9; ++n) {
    s[n] = valid[n] ? (s[n] + bagg) : -1e30f;
    m = fmaxf(m, s[n]);
  }
  float attw[9]; float denom = 0.f;
  #pragma unroll
  for (int n = 0; n < 9; ++n) {
    attw[n] = __builtin_amdgcn_exp2f((s[n] - m) * 1.44269504f);
    denom += attw[n];
  }
  const float inv = __builtin_amdgcn_rcpf(denom);
  #pragma unroll
  for (int n = 0; n < 9; ++n) attw[n] *= inv;   // invalid -> exactly 0

  // ---- weighted encoder sum over this thread's 16 channels ----
  float a16[16];
  #pragma unroll
  for (int e = 0; e < 16; ++e) a16[e] = 0.f;
  #pragma unroll
  for (int n = 0; n < 9; ++n) {
    const short8* ep = (const short8*)(enc_t + ((long)off[n] << 6) + cb);
    const short8 ea = ep[0], eb = ep[1];
    #pragma unroll
    for (int e = 0; e < 8; ++e)
      a16[e] = __builtin_fmaf(attw[n], bf2f((ushort_t)ea[e]), a16[e]);
    #pragma unroll
    for (int e = 0; e < 8; ++e)
      a16[8 + e] = __builtin_fmaf(attw[n], bf2f((ushort_t)eb[e]), a16[8 + e]);
  }
  short8 o0, o1;
  #pragma unroll
  for (int e = 0; e < 8; ++e) {
    o0[e] = (short)f2bf(a16[e]);
    o1[e] = (short)f2bf(a16[8 + e]);
  }
  short8* op = (short8*)(att + ((long)pix << 6) + cb);
  op[0] = o0;
  op[1] = o1;
}

// ---------------------------------------------------------------------------
// Kernel 3: fused conv(3x3 MFMA) + out, TWO rows per block (grid 512).
// Per-kh 48KB staged packedC feeds both rows (4 MFMAs per ds_read);
// two independent accumulation chains per wave double schedulable ILP.
// Zero-pad semantics: OOB rows/pixels contribute zero A-frags.
// ---------------------------------------------------------------------------
__global__ __launch_bounds__(256) void conv_out_kernel(
    const ushort_t* __restrict__ dec_t, const ushort_t* __restrict__ packedC,
    const float* __restrict__ conv_b, const ushort_t* __restrict__ attn_nhwc,
    const ushort_t* __restrict__ packedA, const float* __restrict__ b_attn,
    float* __restrict__ out)
{
  __shared__ ushort_t bsh[24576];            // 48 KB: one kh slice (48 frags)
  ushort_t* vlds = bsh;                      // out-phase alias: 2 rows, stride 72
  const int nwg = gridDim.x;                 // 512, divisible by 8
  const int cpx = nwg >> 3;
  const int bid = blockIdx.x;
  const int grp = (bid & 7) * cpx + (bid >> 3);
  const int b = grp >> 6;                    // 64 row-pairs per batch
  const int h0 = (grp & 63) * 2;
  const int tid = threadIdx.x;
  const int l = tid & 63;
  const int wv = tid >> 6;
  const int pix0 = wv * 32;
  const int col = l & 15, kg = l >> 4;

  // ---- conv phase: acc[row][mf][nf] ----
  f32x4 acc[2][2][4];
  #pragma unroll
  for (int r = 0; r < 2; ++r)
    #pragma unroll
    for (int mf = 0; mf < 2; ++mf)
      #pragma unroll
      for (int nf = 0; nf < 4; ++nf)
        acc[r][mf][nf] = (f32x4){0.f, 0.f, 0.f, 0.f};

  #pragma unroll
  for (int kh = 0; kh < 3; ++kh) {
    // stage this kh's 48 frags (48 KB) into LDS, coalesced
    __syncthreads();                          // prior slice's reads done
    {
      const short8* src = (const short8*)(packedC + (long)kh * 24576);
      #pragma unroll
      for (int i = 0; i < 12; ++i)
        *(short8*)&bsh[(tid + i * 256) * 8] = src[tid + i * 256];
    }
    __syncthreads();

    const int hh0 = h0 + kh - 1;              // input row for r=0
    const bool v0 = (hh0 >= 0);               // h0 even, h0+kh <= 128
    const bool v1 = (h0 + kh <= HH - 1);      // input row for r=1 is hh0+1
    const ushort_t* arow0 = dec_t + ((long)(b * HH + (v0 ? hh0 : 0)) * WW) * DEC_C;
    const ushort_t* arow1 = dec_t + ((long)(b * HH + (v1 ? hh0 + 1 : 0)) * WW) * DEC_C;

    #pragma unroll
    for (int ds = 0; ds < 4; ++ds) {
      const int d0 = ds * 32;
      short8 afr[2][3][2];                    // [row][kw][mf]
      #pragma unroll
      for (int kw = 0; kw < 3; ++kw)
        #pragma unroll
        for (int mf = 0; mf < 2; ++mf) {
          const int wp = pix0 + mf * 16 + col + kw - 1;
          const bool wok = (wp >= 0 && wp < WW);
          short8 z = {0, 0, 0, 0, 0, 0, 0, 0};
          afr[0][kw][mf] = (wok && v0)
              ? *(const short8*)(arow0 + (long)wp * DEC_C + d0 + kg * 8) : z;
          afr[1][kw][mf] = (wok && v1)
              ? *(const short8*)(arow1 + (long)wp * DEC_C + d0 + kg * 8) : z;
        }
      #pragma unroll
      for (int kw = 0; kw < 3; ++kw) {
        #pragma unroll
        for (int nf = 0; nf < 4; ++nf) {
          const short8 bfr =
              *(const short8*)&bsh[(((kw * 4 + ds) * 4 + nf) * 64 + l) * 8];
          #pragma unroll
          for (int r = 0; r < 2; ++r) {
            acc[r][0][nf] = __builtin_amdgcn_mfma_f32_16x16x32_bf16(
                afr[r][kw][0], bfr, acc[r][0][nf], 0, 0, 0);
            acc[r][1][nf] = __builtin_amdgcn_mfma_f32_16x16x32_bf16(
                afr[r][kw][1], bfr, acc[r][1][nf], 0, 0, 0);
          }
        }
      }
    }
  }

  // vals -> LDS bf16 [row*128+pix][c] stride 72 (16B-aligned rows)
  __syncthreads();                            // last slice's B reads done
  #pragma unroll
  for (int r = 0; r < 2; ++r)
    #pragma unroll
    for (int mf = 0; mf < 2; ++mf)
      #pragma unroll
      for (int nf = 0; nf < 4; ++nf)
        #pragma unroll
        for (int rr = 0; rr < 4; ++rr) {
          const int pix = pix0 + mf * 16 + kg * 4 + rr;
          const int c = nf * 16 + col;
          vlds[(r * WW + pix) * 72 + c] = f2bf(acc[r][mf][nf][rr] + conv_b[c]);
        }
  __syncthreads();

  // ---- out phase (swapped: A = W_attn frags, B = cat^T; D = (ch, pix)) ----
  for (int r = 0; r < 2; ++r) {
    const int bh = b * HH + h0 + r;
    f32x4 ao[4][2];
    #pragma unroll
    for (int mf = 0; mf < 4; ++mf)
      #pragma unroll
      for (int pf = 0; pf < 2; ++pf)
        ao[mf][pf] = (f32x4){0.f, 0.f, 0.f, 0.f};

    #pragma unroll
    for (int ks = 0; ks < 4; ++ks) {
      short8 bfr[2];
      #pragma unroll
      for (int pf = 0; pf < 2; ++pf) {
        const int pix = pix0 + pf * 16 + col;
        short8 v;
        if (ks < 2) {
          v = *(const short8*)&vlds[(r * WW + pix) * 72 + ks * 32 + kg * 8];
        } else {
          v = *(const short8*)(attn_nhwc + ((long)bh * WW + pix) * 64 +
                               (ks - 2) * 32 + kg * 8);
        }
        bfr[pf] = v;
      }
      #pragma unroll
      for (int mf = 0; mf < 4; ++mf) {
        const short8 afr =
            *(const short8*)(packedA + ((long)(ks * 4 + mf) * 64 + l) * 8);
        #pragma unroll
        for (int pf = 0; pf < 2; ++pf)
          ao[mf][pf] = __builtin_amdgcn_mfma_f32_16x16x32_bf16(
              afr, bfr[pf], ao[mf][pf], 0, 0, 0);
      }
    }

    // direct NCHW f32 stores
    #pragma unroll
    for (int mf = 0; mf < 4; ++mf)
      #pragma unroll
      for (int pf = 0; pf < 2; ++pf)
        #pragma unroll
        for (int rr = 0; rr < 4; ++rr) {
          const int n = mf * 16 + kg * 4 + rr;
          const int pix = pix0 + pf * 16 + col;
          float o = ao[mf][pf][rr] + b_attn[n];
          o = (o >= 0.f) ? o : 0.2f * o;
          out[((long)(b * ENC_C + n) * HH + (h0 + r)) * WW + pix] = o;
        }
  }
}

// ---------------------------------------------------------------------------
extern "C" void kernel_launch(void* const* d_in, const int* in_sizes, int n_in,
                              void* d_out, int out_size, void* d_ws, size_t ws_size,
                              hipStream_t stream) {
  const float* enc    = (const float*)d_in[0];
  const float* dec    = (const float*)d_in[1];
  const float* W_enc  = (const float*)d_in[2];
  const float* b_enc  = (const float*)d_in[3];
  const float* W_dec  = (const float*)d_in[4];
  const float* b_dec  = (const float*)d_in[5];
  const float* W_agg  = (const float*)d_in[6];
  const float* b_agg  = (const float*)d_in[7];
  const float* W_attn = (const float*)d_in[8];
  const float* b_attn = (const float*)d_in[9];
  const float* conv_w = (const float*)d_in[10];
  const float* conv_b = (const float*)d_in[11];
  float* out = (float*)d_out;

  const long npix = (long)BB * HH * WW;               // 131072
  ushort_t* q_bf    = (ushort_t*)d_ws;                // [npix][64] bf16 NHWC
  ushort_t* k_bf    = q_bf + npix * 64;               // [npix][64]
  ushort_t* enc_t   = k_bf + npix * 64;               // [npix][64]
  ushort_t* dec_t   = enc_t + npix * 64;              // [npix][128]
  ushort_t* att     = dec_t + npix * 128;             // [npix][64]
  ushort_t* packedC = att + npix * 64;                // conv W frags
  ushort_t* packedA = packedC + 144 * 64 * 8;
  ushort_t* packedQ = packedA + 16 * 64 * 8;
  ushort_t* packedK = packedQ + 16 * 64 * 8;

  hipLaunchKernelGGL(pack_w_kernel, dim3(184), dim3(64), 0, stream,
                     conv_w, W_attn, W_dec, W_enc, packedC, packedA, packedQ, packedK);
  hipLaunchKernelGGL(prep_kernel, dim3(BB * HH), dim3(256), 0, stream,
                     enc, dec, packedQ, packedK, b_enc, b_dec, q_bf, k_bf, enc_t, dec_t);
  hipLaunchKernelGGL(attn_kernel, dim3((int)(npix * 4 / 256)), dim3(256), 0, stream,
                     q_bf, k_bf, enc_t, W_agg, b_agg, att);
  hipLaunchKernelGGL(conv_out_kernel, dim3(BB * HH / 2), dim3(256), 0, stream,
                     dec_t, packedC, conv_b, att, packedA, b_attn, out);
}

// Round 11
// 120.504 us; speedup vs baseline: 1.9229x; 1.0208x over previous
//
#include <hip/hip_runtime.h>

#define BB 8
#define ENC_C 64
#define DEC_C 128
#define HH 128
#define WW 128

typedef unsigned short ushort_t;
typedef __attribute__((ext_vector_type(8))) short short8;
typedef __attribute__((ext_vector_type(4))) float f32x4;

static __device__ __forceinline__ ushort_t f2bf(float x) {
  unsigned int u = __builtin_bit_cast(unsigned int, x);
  u += 0x7fff + ((u >> 16) & 1);   // round-to-nearest-even
  return (ushort_t)(u >> 16);
}
static __device__ __forceinline__ float bf2f(ushort_t v) {
  unsigned int u = ((unsigned int)v) << 16;
  return __builtin_bit_cast(float, u);
}

// ---------------------------------------------------------------------------
// Kernel 0: pack weight fragments (bf16).
//   blk 0..143   : conv_w (K=1152)  -> packedC
//   blk 144..159 : W_attn (K=128)   -> packedA
//   blk 160..175 : W_dec  (K=128)   -> packedQ
//   blk 176..183 : W_enc  (K=64)    -> packedK
// Frag: lane l, elem j holds W[k = ks*32 + (l>>4)*8 + j][n = nf*16 + (l&15)].
// ---------------------------------------------------------------------------
__global__ __launch_bounds__(64) void pack_w_kernel(
    const float* __restrict__ conv_w, const float* __restrict__ W_attn,
    const float* __restrict__ W_dec, const float* __restrict__ W_enc,
    ushort_t* __restrict__ packedC, ushort_t* __restrict__ packedA,
    ushort_t* __restrict__ packedQ, ushort_t* __restrict__ packedK)
{
  const int blk = blockIdx.x;
  const int l = threadIdx.x;
  const float* W;
  ushort_t* dst;
  int bb;
  if (blk < 144) {
    const int kstep = blk >> 2, nf = blk & 3;
    const int tap = kstep >> 2, dstep = kstep & 3;
    const int n = nf * 16 + (l & 15);
    const int dbase = dstep * 32 + (l >> 4) * 8;
    ushort_t v[8];
    #pragma unroll
    for (int j = 0; j < 8; ++j)
      v[j] = f2bf(conv_w[(tap * DEC_C + dbase + j) * 64 + n]);
    // layout: [tap][ds][nf] -> slice of 16 frags (16KB) per tap
    ushort_t* d = packedC + (((long)tap * 16 + dstep * 4 + nf) * 64 + l) * 8;
    #pragma unroll
    for (int j = 0; j < 8; ++j) d[j] = v[j];
    return;
  } else if (blk < 160) {
    W = W_attn; dst = packedA; bb = blk - 144;
  } else if (blk < 176) {
    W = W_dec;  dst = packedQ; bb = blk - 160;
  } else {
    W = W_enc;  dst = packedK; bb = blk - 176;
  }
  const int ks = bb >> 2, nf = bb & 3;
  const int n = nf * 16 + (l & 15);
  const int kbase = ks * 32 + (l >> 4) * 8;
  ushort_t v[8];
  #pragma unroll
  for (int j = 0; j < 8; ++j)
    v[j] = f2bf(W[(kbase + j) * 64 + n]);
  ushort_t* d = dst + ((long)bb * 64 + l) * 8;
  #pragma unroll
  for (int j = 0; j < 8; ++j) d[j] = v[j];
}

// ---------------------------------------------------------------------------
// Kernel 1: per (b,h) row. MFMA (A = pixel frags from LDS, B = packed W).
// Outputs q/k NHWC bf16 (+bias), enc_t NHWC bf16, dec_t NHWC bf16.
// No waves-per-EU cap: R6 showed a VGPR cap here spills to scratch.
// ---------------------------------------------------------------------------
__global__ __launch_bounds__(256) void prep_kernel(
    const float* __restrict__ enc, const float* __restrict__ dec,
    const ushort_t* __restrict__ packedQ, const ushort_t* __restrict__ packedK,
    const float* __restrict__ b_enc, const float* __restrict__ b_dec,
    ushort_t* __restrict__ q_nhwc, ushort_t* __restrict__ k_nhwc,
    ushort_t* __restrict__ enc_t, ushort_t* __restrict__ dec_t)
{
  __shared__ float smem[WW * 68];
  const int bh = blockIdx.x;
  const int b = bh >> 7, h = bh & 127;
  const int tid = threadIdx.x;
  const int l = tid & 63;
  const int wv = tid >> 6;
  const int pix0 = wv * 32;
  const int col = l & 15, kg = l >> 4;

  // ---- encoder tile [w][c] f32 ----
  #pragma unroll
  for (int i = 0; i < 32; ++i) {
    int idx = tid + i * 256;
    int cc = idx >> 7, wl = idx & 127;
    smem[wl * 68 + cc] = enc[((b * ENC_C + cc) * HH + h) * WW + wl];
  }
  __syncthreads();

  // enc_t NHWC bf16
  #pragma unroll
  for (int i = 0; i < 32; ++i) {
    int idx = tid + i * 256;
    int wl = idx >> 6, cc = idx & 63;
    enc_t[((long)bh * WW + wl) * 64 + cc] = f2bf(smem[wl * 68 + cc]);
  }

  // k = enc @ W_enc  (A = pixels, D row = pixel -> NHWC)
  f32x4 acck[2][4];
  #pragma unroll
  for (int mf = 0; mf < 2; ++mf)
    #pragma unroll
    for (int nf = 0; nf < 4; ++nf)
      acck[mf][nf] = (f32x4){0.f, 0.f, 0.f, 0.f};

  #pragma unroll
  for (int ks = 0; ks < 2; ++ks) {
    short8 afr[2];
    #pragma unroll
    for (int mf = 0; mf < 2; ++mf) {
      const int pix = pix0 + mf * 16 + col;
      const float4* p = (const float4*)&smem[pix * 68 + ks * 32 + kg * 8];
      float4 x0 = p[0], x1 = p[1];
      short8 v;
      v[0] = (short)f2bf(x0.x); v[1] = (short)f2bf(x0.y);
      v[2] = (short)f2bf(x0.z); v[3] = (short)f2bf(x0.w);
      v[4] = (short)f2bf(x1.x); v[5] = (short)f2bf(x1.y);
      v[6] = (short)f2bf(x1.z); v[7] = (short)f2bf(x1.w);
      afr[mf] = v;
    }
    #pragma unroll
    for (int nf = 0; nf < 4; ++nf) {
      const short8 bfr =
          *(const short8*)(packedK + ((long)(ks * 4 + nf) * 64 + l) * 8);
      acck[0][nf] = __builtin_amdgcn_mfma_f32_16x16x32_bf16(
          afr[0], bfr, acck[0][nf], 0, 0, 0);
      acck[1][nf] = __builtin_amdgcn_mfma_f32_16x16x32_bf16(
          afr[1], bfr, acck[1][nf], 0, 0, 0);
    }
  }
  // store k NHWC bf16
  #pragma unroll
  for (int mf = 0; mf < 2; ++mf)
    #pragma unroll
    for (int nf = 0; nf < 4; ++nf)
      #pragma unroll
      for (int r = 0; r < 4; ++r) {
        const int pix = pix0 + mf * 16 + kg * 4 + r;
        const int c = nf * 16 + col;
        k_nhwc[((long)bh * WW + pix) * 64 + c] = f2bf(acck[mf][nf][r] + b_enc[c]);
      }
  __syncthreads();

  // ---- decoder tile, two 64-channel halves ----
  f32x4 accq[2][4];
  #pragma unroll
  for (int mf = 0; mf < 2; ++mf)
    #pragma unroll
    for (int nf = 0; nf < 4; ++nf)
      accq[mf][nf] = (f32x4){0.f, 0.f, 0.f, 0.f};

  #pragma unroll
  for (int hf = 0; hf < 2; ++hf) {
    #pragma unroll
    for (int i = 0; i < 32; ++i) {
      int idx = tid + i * 256;
      int cc = idx >> 7, wl = idx & 127;
      smem[wl * 68 + cc] = dec[((b * DEC_C + hf * 64 + cc) * HH + h) * WW + wl];
    }
    __syncthreads();

    // dec_t NHWC bf16
    #pragma unroll
    for (int i = 0; i < 32; ++i) {
      int idx = tid + i * 256;
      int wl = idx >> 6, cc = idx & 63;
      dec_t[((long)bh * WW + wl) * DEC_C + hf * 64 + cc] =
          f2bf(smem[wl * 68 + cc]);
    }

    #pragma unroll
    for (int ks2 = 0; ks2 < 2; ++ks2) {
      const int ks = hf * 2 + ks2;
      short8 afr[2];
      #pragma unroll
      for (int mf = 0; mf < 2; ++mf) {
        const int pix = pix0 + mf * 16 + col;
        const float4* p = (const float4*)&smem[pix * 68 + ks2 * 32 + kg * 8];
        float4 x0 = p[0], x1 = p[1];
        short8 v;
        v[0] = (short)f2bf(x0.x); v[1] = (short)f2bf(x0.y);
        v[2] = (short)f2bf(x0.z); v[3] = (short)f2bf(x0.w);
        v[4] = (short)f2bf(x1.x); v[5] = (short)f2bf(x1.y);
        v[6] = (short)f2bf(x1.z); v[7] = (short)f2bf(x1.w);
        afr[mf] = v;
      }
      #pragma unroll
      for (int nf = 0; nf < 4; ++nf) {
        const short8 bfr =
            *(const short8*)(packedQ + ((long)(ks * 4 + nf) * 64 + l) * 8);
        accq[0][nf] = __builtin_amdgcn_mfma_f32_16x16x32_bf16(
            afr[0], bfr, accq[0][nf], 0, 0, 0);
        accq[1][nf] = __builtin_amdgcn_mfma_f32_16x16x32_bf16(
            afr[1], bfr, accq[1][nf], 0, 0, 0);
      }
    }
    __syncthreads();
  }

  // store q NHWC bf16
  #pragma unroll
  for (int mf = 0; mf < 2; ++mf)
    #pragma unroll
    for (int nf = 0; nf < 4; ++nf)
      #pragma unroll
      for (int r = 0; r < 4; ++r) {
        const int pix = pix0 + mf * 16 + kg * 4 + r;
        const int c = nf * 16 + col;
        q_nhwc[((long)bh * WW + pix) * 64 + c] = f2bf(accq[mf][nf][r] + b_dec[c]);
      }
}

// ---------------------------------------------------------------------------
// Kernel 2: attention, FOUR threads per pixel (16 channels each).
// ---------------------------------------------------------------------------
__global__ __launch_bounds__(256) void attn_kernel(
    const ushort_t* __restrict__ q_nhwc, const ushort_t* __restrict__ k_nhwc,
    const ushort_t* __restrict__ enc_t, const float* __restrict__ W_agg,
    const float* __restrict__ b_agg, ushort_t* __restrict__ att)
{
  const int nwg = gridDim.x;                 // 2048, divisible by 8
  const int cpx = nwg >> 3;
  const int bid = blockIdx.x;
  const int swz = (bid & 7) * cpx + (bid >> 3);   // XCD-contiguous pixels
  const int t = swz * 256 + threadIdx.x;     // 0 .. 4*npix-1
  const int pix = t >> 2;
  const int cb = (t & 3) * 16;               // this thread's channel base
  const int h = (pix >> 7) & 127;
  const int w = pix & 127;

  int off[9]; bool valid[9];
  #pragma unroll
  for (int n = 0; n < 9; ++n) {
    const int dh = n / 3 - 1, dw = n % 3 - 1;
    const int nh = h + dh, nw = w + dw;
    valid[n] = (nh >= 0 && nh < HH && nw >= 0 && nw < WW);
    const int nhc = min(max(nh, 0), HH - 1);
    const int nwc = min(max(nw, 0), WW - 1);
    off[n] = (pix & ~16383) + nhc * WW + nwc;  // same batch, clamped pixel
  }

  const short8* qp = (const short8*)(q_nhwc + ((long)pix << 6) + cb);
  const short8 qa = qp[0], qb = qp[1];

  float wa[16];
  {
    float4 w0 = *(const float4*)(W_agg + cb);
    float4 w1 = *(const float4*)(W_agg + cb + 4);
    float4 w2 = *(const float4*)(W_agg + cb + 8);
    float4 w3 = *(const float4*)(W_agg + cb + 12);
    wa[0]=w0.x; wa[1]=w0.y; wa[2]=w0.z; wa[3]=w0.w;
    wa[4]=w1.x; wa[5]=w1.y; wa[6]=w1.z; wa[7]=w1.w;
    wa[8]=w2.x; wa[9]=w2.y; wa[10]=w2.z; wa[11]=w2.w;
    wa[12]=w3.x; wa[13]=w3.y; wa[14]=w3.z; wa[15]=w3.w;
  }

  // ---- score partials over this thread's 16 channels ----
  float s[9];
  #pragma unroll
  for (int n = 0; n < 9; ++n) {
    const short8* kp = (const short8*)(k_nhwc + ((long)off[n] << 6) + cb);
    const short8 ka = kp[0], kb = kp[1];
    float sc = 0.f;
    #pragma unroll
    for (int e = 0; e < 8; ++e) {
      float x = bf2f((ushort_t)qa[e]) + bf2f((ushort_t)ka[e]);
      x = fminf(fmaxf(x, -15.f), 15.f);
      float z = __builtin_amdgcn_exp2f(x * 2.88539008f);
      float tt = __builtin_fmaf(-2.f, __builtin_amdgcn_rcpf(z + 1.f), 1.f);
      sc = __builtin_fmaf(tt, wa[e], sc);
    }
    #pragma unroll
    for (int e = 0; e < 8; ++e) {
      float x = bf2f((ushort_t)qb[e]) + bf2f((ushort_t)kb[e]);
      x = fminf(fmaxf(x, -15.f), 15.f);
      float z = __builtin_amdgcn_exp2f(x * 2.88539008f);
      float tt = __builtin_fmaf(-2.f, __builtin_amdgcn_rcpf(z + 1.f), 1.f);
      sc = __builtin_fmaf(tt, wa[8 + e], sc);
    }
    s[n] = sc;
  }

  // ---- combine partials across the 4 lanes of this pixel ----
  #pragma unroll
  for (int n = 0; n < 9; ++n) {
    s[n] += __shfl_xor(s[n], 1);
    s[n] += __shfl_xor(s[n], 2);
  }

  // ---- masked softmax (duplicated in all 4 lanes) ----
  const float bagg = b_agg[0];
  float m = -1e30f;
  #pragma unroll
  for (int n = 0; n < 9; ++n) {
    s[n] = valid[n] ? (s[n] + bagg) : -1e30f;
    m = fmaxf(m, s[n]);
  }
  float attw[9]; float denom = 0.f;
  #pragma unroll
  for (int n = 0; n < 9; ++n) {
    attw[n] = __builtin_amdgcn_exp2f((s[n] - m) * 1.44269504f);
    denom += attw[n];
  }
  const float inv = __builtin_amdgcn_rcpf(denom);
  #pragma unroll
  for (int n = 0; n < 9; ++n) attw[n] *= inv;   // invalid -> exactly 0

  // ---- weighted encoder sum over this thread's 16 channels ----
  float a16[16];
  #pragma unroll
  for (int e = 0; e < 16; ++e) a16[e] = 0.f;
  #pragma unroll
  for (int n = 0; n < 9; ++n) {
    const short8* ep = (const short8*)(enc_t + ((long)off[n] << 6) + cb);
    const short8 ea = ep[0], eb = ep[1];
    #pragma unroll
    for (int e = 0; e < 8; ++e)
      a16[e] = __builtin_fmaf(attw[n], bf2f((ushort_t)ea[e]), a16[e]);
    #pragma unroll
    for (int e = 0; e < 8; ++e)
      a16[8 + e] = __builtin_fmaf(attw[n], bf2f((ushort_t)eb[e]), a16[8 + e]);
  }
  short8 o0, o1;
  #pragma unroll
  for (int e = 0; e < 8; ++e) {
    o0[e] = (short)f2bf(a16[e]);
    o1[e] = (short)f2bf(a16[8 + e]);
  }
  short8* op = (short8*)(att + ((long)pix << 6) + cb);
  op[0] = o0;
  op[1] = o1;
}

// ---------------------------------------------------------------------------
// Kernel 3: fused conv(3x3 MFMA) + out, ONE row/block (grid 1024 = 4/CU).
// 9-phase pipeline: per tap (kh,kw), double-buffered 16KB async staging of
// packedC via global_load_lds (issued for tap p+1, consumed in phase p+1 —
// loads are in flight across the compute of phase p). vlds aliases staging.
// ---------------------------------------------------------------------------
__global__ __launch_bounds__(256) void conv_out_kernel(
    const ushort_t* __restrict__ dec_t, const ushort_t* __restrict__ packedC,
    const float* __restrict__ conv_b, const ushort_t* __restrict__ attn_nhwc,
    const ushort_t* __restrict__ packedA, const float* __restrict__ b_attn,
    float* __restrict__ out)
{
  __shared__ ushort_t bsh[16384];            // 32 KB: 2 x 16KB tap buffers
  ushort_t* vlds = bsh;                      // out-phase alias, stride 72
  const int nwg = gridDim.x;                 // 1024, divisible by 8
  const int cpx = nwg >> 3;
  const int bid = blockIdx.x;
  const int bh = (bid & 7) * cpx + (bid >> 3);
  const int b = bh >> 7, h = bh & 127;
  const int tid = threadIdx.x;
  const int l = tid & 63;
  const int wv = tid >> 6;
  const int pix0 = wv * 32;
  const int col = l & 15, kg = l >> 4;

  // async-stage tap slice (16 frags = 16KB) into buf[tap&1]
  auto stage = [&](int tap) {
    const ushort_t* src = packedC + (long)tap * 8192;
    ushort_t* dstb = bsh + (tap & 1) * 8192 + (long)(tid & ~63) * 8;
    #pragma unroll
    for (int i = 0; i < 4; ++i) {
      __builtin_amdgcn_global_load_lds(
          (const __attribute__((address_space(1))) void*)(src + (long)(i * 256 + tid) * 8),
          (__attribute__((address_space(3))) void*)(dstb + i * 256 * 8),
          16, 0, 0);
    }
  };

  // ---- conv phase: 9-tap pipeline ----
  f32x4 acc[2][4];
  #pragma unroll
  for (int mf = 0; mf < 2; ++mf)
    #pragma unroll
    for (int nf = 0; nf < 4; ++nf)
      acc[mf][nf] = (f32x4){0.f, 0.f, 0.f, 0.f};

  stage(0);

  #pragma unroll
  for (int p = 0; p < 9; ++p) {
    __syncthreads();                         // buf[p&1] staged; prior reads done
    if (p + 1 < 9) stage(p + 1);             // async loads fly across compute
    const int kh = p / 3, kw = p % 3;
    const int hh = h + kh - 1;
    if (hh >= 0 && hh < HH) {                // block-uniform skip
      const ushort_t* arow = dec_t + ((long)(b * HH + hh) * WW) * DEC_C;
      const ushort_t* bbase = bsh + (p & 1) * 8192;
      short8 afr[4][2];
      #pragma unroll
      for (int ds = 0; ds < 4; ++ds)
        #pragma unroll
        for (int mf = 0; mf < 2; ++mf) {
          const int wp = pix0 + mf * 16 + col + kw - 1;
          short8 z = {0, 0, 0, 0, 0, 0, 0, 0};
          afr[ds][mf] = (wp >= 0 && wp < WW)
              ? *(const short8*)(arow + (long)wp * DEC_C + ds * 32 + kg * 8) : z;
        }
      #pragma unroll
      for (int ds = 0; ds < 4; ++ds)
        #pragma unroll
        for (int nf = 0; nf < 4; ++nf) {
          const short8 bfr =
              *(const short8*)(bbase + ((ds * 4 + nf) * 64 + l) * 8);
          acc[0][nf] = __builtin_amdgcn_mfma_f32_16x16x32_bf16(
              afr[ds][0], bfr, acc[0][nf], 0, 0, 0);
          acc[1][nf] = __builtin_amdgcn_mfma_f32_16x16x32_bf16(
              afr[ds][1], bfr, acc[1][nf], 0, 0, 0);
        }
    }
  }

  // vals -> LDS bf16 [pix][c] stride 72 (16B-aligned rows)
  __syncthreads();                            // last phase's reads done
  #pragma unroll
  for (int mf = 0; mf < 2; ++mf)
    #pragma unroll
    for (int nf = 0; nf < 4; ++nf)
      #pragma unroll
      for (int r = 0; r < 4; ++r) {
        const int pix = pix0 + mf * 16 + kg * 4 + r;
        const int c = nf * 16 + col;
        vlds[pix * 72 + c] = f2bf(acc[mf][nf][r] + conv_b[c]);
      }
  __syncthreads();

  // ---- out phase (swapped: A = W_attn frags, B = cat^T; D = (ch, pix)) ----
  f32x4 ao[4][2];
  #pragma unroll
  for (int mf = 0; mf < 4; ++mf)
    #pragma unroll
    for (int pf = 0; pf < 2; ++pf)
      ao[mf][pf] = (f32x4){0.f, 0.f, 0.f, 0.f};

  #pragma unroll
  for (int ks = 0; ks < 4; ++ks) {
    short8 bfr[2];
    #pragma unroll
    for (int pf = 0; pf < 2; ++pf) {
      const int pix = pix0 + pf * 16 + col;
      short8 v;
      if (ks < 2) {
        v = *(const short8*)&vlds[pix * 72 + ks * 32 + kg * 8];  // b128
      } else {
        v = *(const short8*)(attn_nhwc + ((long)bh * WW + pix) * 64 +
                             (ks - 2) * 32 + kg * 8);
      }
      bfr[pf] = v;
    }
    #pragma unroll
    for (int mf = 0; mf < 4; ++mf) {
      const short8 afr =
          *(const short8*)(packedA + ((long)(ks * 4 + mf) * 64 + l) * 8);
      #pragma unroll
      for (int pf = 0; pf < 2; ++pf)
        ao[mf][pf] = __builtin_amdgcn_mfma_f32_16x16x32_bf16(
            afr, bfr[pf], ao[mf][pf], 0, 0, 0);
    }
  }

  // direct NCHW f32 stores
  #pragma unroll
  for (int mf = 0; mf < 4; ++mf)
    #pragma unroll
    for (int pf = 0; pf < 2; ++pf)
      #pragma unroll
      for (int r = 0; r < 4; ++r) {
        const int n = mf * 16 + kg * 4 + r;
        const int pix = pix0 + pf * 16 + col;
        float o = ao[mf][pf][r] + b_attn[n];
        o = (o >= 0.f) ? o : 0.2f * o;
        out[((long)(b * ENC_C + n) * HH + h) * WW + pix] = o;
      }
}

// ---------------------------------------------------------------------------
extern "C" void kernel_launch(void* const* d_in, const int* in_sizes, int n_in,
                              void* d_out, int out_size, void* d_ws, size_t ws_size,
                              hipStream_t stream) {
  const float* enc    = (const float*)d_in[0];
  const float* dec    = (const float*)d_in[1];
  const float* W_enc  = (const float*)d_in[2];
  const float* b_enc  = (const float*)d_in[3];
  const float* W_dec  = (const float*)d_in[4];
  const float* b_dec  = (const float*)d_in[5];
  const float* W_agg  = (const float*)d_in[6];
  const float* b_agg  = (const float*)d_in[7];
  const float* W_attn = (const float*)d_in[8];
  const float* b_attn = (const float*)d_in[9];
  const float* conv_w = (const float*)d_in[10];
  const float* conv_b = (const float*)d_in[11];
  float* out = (float*)d_out;

  const long npix = (long)BB * HH * WW;               // 131072
  ushort_t* q_bf    = (ushort_t*)d_ws;                // [npix][64] bf16 NHWC
  ushort_t* k_bf    = q_bf + npix * 64;               // [npix][64]
  ushort_t* enc_t   = k_bf + npix * 64;               // [npix][64]
  ushort_t* dec_t   = enc_t + npix * 64;              // [npix][128]
  ushort_t* att     = dec_t + npix * 128;             // [npix][64]
  ushort_t* packedC = att + npix * 64;                // conv W frags
  ushort_t* packedA = packedC + 144 * 64 * 8;
  ushort_t* packedQ = packedA + 16 * 64 * 8;
  ushort_t* packedK = packedQ + 16 * 64 * 8;

  hipLaunchKernelGGL(pack_w_kernel, dim3(184), dim3(64), 0, stream,
                     conv_w, W_attn, W_dec, W_enc, packedC, packedA, packedQ, packedK);
  hipLaunchKernelGGL(prep_kernel, dim3(BB * HH), dim3(256), 0, stream,
                     enc, dec, packedQ, packedK, b_enc, b_dec, q_bf, k_bf, enc_t, dec_t);
  hipLaunchKernelGGL(attn_kernel, dim3((int)(npix * 4 / 256)), dim3(256), 0, stream,
                     q_bf, k_bf, enc_t, W_agg, b_agg, att);
  hipLaunchKernelGGL(conv_out_kernel, dim3(BB * HH), dim3(256), 0, stream,
                     dec_t, packedC, conv_b, att, packedA, b_attn, out);
}